// Round 4
// baseline (1854.706 us; speedup 1.0000x reference)
//
#include <hip/hip_runtime.h>
#include <hip/hip_bf16.h>

#define N_NODES 50000
#define N_EDGES 800000
#define IN_C    512
#define HID_C   256
#define OUT_C   40
#define BN_EPS  1e-5f
#define N_CHUNK ((N_NODES + 255) / 256)   // 196

// ---------------- static device buffers ----------------
__device__ float g_x   [N_NODES * IN_C];
__device__ float g_A   [N_NODES * HID_C];
__device__ float g_B   [N_NODES * HID_C];
__device__ float g_w0  [IN_C  * HID_C];
__device__ float g_w1  [HID_C * HID_C];
__device__ float g_w2  [HID_C * OUT_C];
__device__ float g_bias[2 * HID_C + OUT_C];
__device__ float g_bnp [4 * HID_C];
__device__ float g_lab [2 * N_NODES * OUT_C];
__device__ float g_40a [N_NODES * OUT_C];
__device__ float g_40b [N_NODES * OUT_C];
__device__ float g_deg [N_NODES];
__device__ float g_dinv[N_NODES];
__device__ int   g_cnt [N_NODES];
__device__ int   g_fill[N_NODES];
__device__ int   g_rowptr[N_NODES + 1];
__device__ int   g_colidx[N_EDGES];
__device__ float g_normv [N_EDGES];
__device__ float g_bnstat[4 * HID_C];
__device__ float g_bnss  [4 * HID_C];
__device__ int   g_csum[256];
__device__ int   g_cpre[256];
__device__ int   g_f32flag[16];   // per-input: 1 if stored fp32, 0 if bf16
__device__ int   g_idx64;         // 1 if edge_index stored int64

// ---------------- helpers ----------------
__device__ __forceinline__ float bf2f(unsigned short u) {
    union { unsigned int i; float f; } v;
    v.i = ((unsigned int)u) << 16;
    return v.f;
}
__device__ __forceinline__ int load_row(const void* ei, int e) {
    if (g_idx64) return (int)((const long long*)ei)[e];
    return ((const int*)ei)[e];
}
__device__ __forceinline__ int load_col(const void* ei, int e) {
    if (g_idx64) return (int)((const long long*)ei)[N_EDGES + e];
    return ((const int*)ei)[N_EDGES + e];
}
__device__ __forceinline__ float load_w(const void* ew, int e) {
    if (g_f32flag[4]) return ((const float*)ew)[e];
    return bf2f(((const unsigned short*)ew)[e]);
}

// ---------------- dtype detection (verified correct in round 2) ----------------
// fp32 data viewed as ushorts: even ushorts are fp32 low-mantissa halves ->
// either random with huge bf16-exponents (random data) or exactly zero
// (exact values like 1.0f) while odd ushorts are nonzero.
__global__ void detect_dtype(const unsigned short* __restrict__ p, int n, int slot) {
    __shared__ int big, evennz, oddnz;
    if (threadIdx.x == 0) { big = 0; evennz = 0; oddnz = 0; }
    __syncthreads();
    int samples = n < 8192 ? n : 8192;
    for (int i = threadIdx.x; i < samples; i += 256) {
        unsigned short u = p[i];
        int e = (u >> 7) & 0xFF;
        if ((i & 1) == 0) {
            if (u) atomicOr(&evennz, 1);
            if (e >= 143) atomicOr(&big, 1);   // |v| >= 2^16 impossible as bf16 here
        } else {
            if (u) atomicOr(&oddnz, 1);
        }
    }
    __syncthreads();
    if (threadIdx.x == 0) g_f32flag[slot] = (big || (!evennz && oddnz)) ? 1 : 0;
}

// int64 edge_index: every odd 32-bit word (high half) is zero.
__global__ void detect_idx(const int* __restrict__ ei) {
    __shared__ int nz;
    if (threadIdx.x == 0) nz = 0;
    __syncthreads();
    for (int i = threadIdx.x; i < 65536; i += 256) {
        if (ei[2 * i + 1] != 0) atomicOr(&nz, 1);
    }
    __syncthreads();
    if (threadIdx.x == 0) g_idx64 = nz ? 0 : 1;
}

// convert (bf16 or fp32, per flag) -> fp32
__global__ void cvt_any(const unsigned short* __restrict__ in, float* __restrict__ out,
                        int n, int slot) {
    int i = blockIdx.x * blockDim.x + threadIdx.x;
    if (i >= n) return;
    if (g_f32flag[slot]) out[i] = ((const float*)in)[i];
    else                 out[i] = bf2f(in[i]);
}

// ---------------- graph build ----------------
__global__ void deg_count(const void* __restrict__ ei, const void* __restrict__ w) {
    int e = blockIdx.x * blockDim.x + threadIdx.x;
    if (e < N_EDGES) {
        int r = load_row(ei, e);
        atomicAdd(&g_deg[r], load_w(w, e));
        atomicAdd(&g_cnt[r], 1);
    }
}

__global__ void dinv_kernel() {
    int i = blockIdx.x * blockDim.x + threadIdx.x;
    if (i < N_NODES) {
        float d = g_deg[i] + 1.0f;   // + self-loop weight 1
        g_dinv[i] = (d > 0.f) ? rsqrtf(fmaxf(d, 1e-12f)) : 0.f;
    }
}

// hierarchical exclusive scan of g_cnt -> g_rowptr
__global__ __launch_bounds__(256) void chunk_sum() {
    __shared__ int sh[256];
    int i = blockIdx.x * 256 + threadIdx.x;
    sh[threadIdx.x] = (i < N_NODES) ? g_cnt[i] : 0;
    __syncthreads();
    for (int s = 128; s > 0; s >>= 1) {
        if (threadIdx.x < s) sh[threadIdx.x] += sh[threadIdx.x + s];
        __syncthreads();
    }
    if (threadIdx.x == 0) g_csum[blockIdx.x] = sh[0];
}
__global__ void chunk_scan() {
    int acc = 0;
    for (int b = 0; b < N_CHUNK; ++b) { g_cpre[b] = acc; acc += g_csum[b]; }
    g_rowptr[N_NODES] = acc;
}
__global__ __launch_bounds__(256) void local_scan() {
    __shared__ int woff[4];
    int t = threadIdx.x, lane = t & 63, wv = t >> 6;
    int i = blockIdx.x * 256 + t;
    int v = (i < N_NODES) ? g_cnt[i] : 0;
    int x = v;
    #pragma unroll
    for (int off = 1; off < 64; off <<= 1) {
        int y = __shfl_up(x, off);
        if (lane >= off) x += y;
    }
    if (lane == 63) woff[wv] = x;
    __syncthreads();
    if (t == 0) {
        int a = 0;
        #pragma unroll
        for (int w = 0; w < 4; ++w) { int tmp = woff[w]; woff[w] = a; a += tmp; }
    }
    __syncthreads();
    if (i < N_NODES) g_rowptr[i] = g_cpre[blockIdx.x] + woff[wv] + (x - v);
}

__global__ void fill_kernel(const void* __restrict__ ei, const void* __restrict__ w) {
    int e = blockIdx.x * blockDim.x + threadIdx.x;
    if (e < N_EDGES) {
        int r = load_row(ei, e), c = load_col(ei, e);
        int pos = g_rowptr[r] + atomicAdd(&g_fill[r], 1);
        g_colidx[pos] = c;
        g_normv[pos]  = g_dinv[r] * load_w(w, e) * g_dinv[c];
    }
}

// ---------------- fp32 tiled SGEMM: C[M,N] = A[M,K] @ B[K,N] ----------------
__global__ __launch_bounds__(256) void sgemm(const float* __restrict__ A, const float* __restrict__ B,
                                             float* __restrict__ C, int M, int N, int K) {
    __shared__ float As[16][68];
    __shared__ float Bs[16][68];
    int tid = threadIdx.x;
    int m0 = blockIdx.x * 64;
    int n0 = blockIdx.y * 64;
    int tx = tid & 15;
    int ty = tid >> 4;
    int ar = tid >> 2;
    int ac = (tid & 3) * 4;
    int br = tid >> 6;
    int bc = tid & 63;
    float acc[4][4] = {{0.f}};
    for (int k0 = 0; k0 < K; k0 += 16) {
        float4 av;
        if (m0 + ar < M) av = *(const float4*)(A + (size_t)(m0 + ar) * K + k0 + ac);
        else             av = make_float4(0.f, 0.f, 0.f, 0.f);
        As[ac + 0][ar] = av.x; As[ac + 1][ar] = av.y; As[ac + 2][ar] = av.z; As[ac + 3][ar] = av.w;
        #pragma unroll
        for (int rr = 0; rr < 4; ++rr) {
            int kk = br + rr * 4;
            int nn = n0 + bc;
            Bs[kk][bc] = (nn < N) ? B[(size_t)(k0 + kk) * N + nn] : 0.f;
        }
        __syncthreads();
        #pragma unroll
        for (int k = 0; k < 16; ++k) {
            float4 a = *(const float4*)&As[k][ty * 4];
            float4 b = *(const float4*)&Bs[k][tx * 4];
            acc[0][0] += a.x * b.x; acc[0][1] += a.x * b.y; acc[0][2] += a.x * b.z; acc[0][3] += a.x * b.w;
            acc[1][0] += a.y * b.x; acc[1][1] += a.y * b.y; acc[1][2] += a.y * b.z; acc[1][3] += a.y * b.w;
            acc[2][0] += a.z * b.x; acc[2][1] += a.z * b.y; acc[2][2] += a.z * b.z; acc[2][3] += a.z * b.w;
            acc[3][0] += a.w * b.x; acc[3][1] += a.w * b.y; acc[3][2] += a.w * b.z; acc[3][3] += a.w * b.w;
        }
        __syncthreads();
    }
    #pragma unroll
    for (int i = 0; i < 4; ++i) {
        int m = m0 + ty * 4 + i;
        if (m < M) {
            #pragma unroll
            for (int j = 0; j < 4; ++j) {
                int n = n0 + tx * 4 + j;
                if (n < N) C[(size_t)m * N + n] = acc[i][j];
            }
        }
    }
}

// ---------------- propagation (CSR gather) ----------------
__global__ __launch_bounds__(256) void prop256(const float* __restrict__ h, float* __restrict__ out,
                                               const float* __restrict__ bias) {
    int i = blockIdx.x;
    int c = threadIdx.x;
    float di  = g_dinv[i];
    float acc = di * di * h[(size_t)i * HID_C + c];
    int s = g_rowptr[i], e = g_rowptr[i + 1];
    for (int k = s; k < e; ++k) {
        int   j  = g_colidx[k];
        float nv = g_normv[k];
        acc += nv * h[(size_t)j * HID_C + c];
    }
    out[(size_t)i * HID_C + c] = acc + bias[c];
}

__global__ __launch_bounds__(64) void prop40(const float* __restrict__ h, float* __restrict__ out,
                                             const float* __restrict__ bias) {
    int i = blockIdx.x;
    int c = threadIdx.x;
    if (c >= OUT_C) return;
    float di  = g_dinv[i];
    float acc = di * di * h[i * OUT_C + c];
    int s = g_rowptr[i], e = g_rowptr[i + 1];
    for (int k = s; k < e; ++k) {
        acc += g_normv[k] * h[g_colidx[k] * OUT_C + c];
    }
    if (bias) acc += bias[c];
    out[i * OUT_C + c] = acc;
}

// ---------------- batchnorm ----------------
__global__ __launch_bounds__(256) void bn_stats(const float* __restrict__ h, int layer) {
    int c = threadIdx.x;
    float s = 0.f, ss = 0.f;
    for (int i = blockIdx.x; i < N_NODES; i += gridDim.x) {
        float v = h[(size_t)i * HID_C + c];
        s += v; ss += v * v;
    }
    atomicAdd(&g_bnstat[layer * 512 + c], s);
    atomicAdd(&g_bnstat[layer * 512 + 256 + c], ss);
}

__global__ void bn_final(int layer) {
    int c = threadIdx.x;
    float sum = g_bnstat[layer * 512 + c];
    float ss  = g_bnstat[layer * 512 + 256 + c];
    float mu  = sum / (float)N_NODES;
    float var = fmaxf(ss / (float)N_NODES - mu * mu, 0.f);
    float gamma = g_bnp[layer * 512 + c];
    float beta  = g_bnp[layer * 512 + 256 + c];
    float scale = gamma * rsqrtf(var + BN_EPS);
    g_bnss[layer * 512 + c]       = scale;
    g_bnss[layer * 512 + 256 + c] = beta - mu * scale;
}

__global__ void bn_apply(float* __restrict__ h, int layer) {
    int idx = blockIdx.x * blockDim.x + threadIdx.x;
    if (idx < N_NODES * HID_C) {
        int c = idx & (HID_C - 1);
        float v = h[idx] * g_bnss[layer * 512 + c] + g_bnss[layer * 512 + 256 + c];
        h[idx] = fmaxf(v, 0.f);
    }
}

// ---------------- host ----------------
template <typename T>
static T* symaddr(const void* sym) {
    void* p = nullptr;
    (void)hipGetSymbolAddress(&p, sym);
    return (T*)p;
}

extern "C" void kernel_launch(void* const* d_in, const int* in_sizes, int n_in,
                              void* d_out, int out_size, void* d_ws, size_t ws_size,
                              hipStream_t stream) {
    const void* ei = d_in[1];

    float* px    = symaddr<float>(HIP_SYMBOL(g_x));
    float* pA    = symaddr<float>(HIP_SYMBOL(g_A));
    float* pB    = symaddr<float>(HIP_SYMBOL(g_B));
    float* pw0   = symaddr<float>(HIP_SYMBOL(g_w0));
    float* pw1   = symaddr<float>(HIP_SYMBOL(g_w1));
    float* pw2   = symaddr<float>(HIP_SYMBOL(g_w2));
    float* pbias = symaddr<float>(HIP_SYMBOL(g_bias));
    float* pbnp  = symaddr<float>(HIP_SYMBOL(g_bnp));
    float* plab  = symaddr<float>(HIP_SYMBOL(g_lab));
    float* p40a  = symaddr<float>(HIP_SYMBOL(g_40a));
    float* p40b  = symaddr<float>(HIP_SYMBOL(g_40b));
    float* pdeg  = symaddr<float>(HIP_SYMBOL(g_deg));
    int*   pcnt  = symaddr<int>(HIP_SYMBOL(g_cnt));
    int*   pfil  = symaddr<int>(HIP_SYMBOL(g_fill));
    float* pbst  = symaddr<float>(HIP_SYMBOL(g_bnstat));

    hipMemsetAsync(pdeg, 0, N_NODES * sizeof(float), stream);
    hipMemsetAsync(pcnt, 0, N_NODES * sizeof(int),   stream);
    hipMemsetAsync(pfil, 0, N_NODES * sizeof(int),   stream);
    hipMemsetAsync(pbst, 0, 4 * HID_C * sizeof(float), stream);

    detect_idx<<<1, 256, 0, stream>>>((const int*)ei);
    const int fslots[] = {0, 2, 3, 4, 5, 6, 7, 8, 9, 10, 11, 12, 13, 14};
    for (int s : fslots)
        detect_dtype<<<1, 256, 0, stream>>>((const unsigned short*)d_in[s], in_sizes[s], s);

    auto cvt = [&](int slot, float* out, int n) {
        cvt_any<<<(n + 255) / 256, 256, 0, stream>>>((const unsigned short*)d_in[slot], out, n, slot);
    };
    cvt(0,  px,              N_NODES * IN_C);
    cvt(5,  pw0,             IN_C * HID_C);
    cvt(7,  pw1,             HID_C * HID_C);
    cvt(9,  pw2,             HID_C * OUT_C);
    cvt(6,  pbias,           HID_C);
    cvt(8,  pbias + HID_C,   HID_C);
    cvt(10, pbias + 2*HID_C, OUT_C);
    cvt(11, pbnp,            HID_C);
    cvt(12, pbnp + HID_C,    HID_C);
    cvt(13, pbnp + 2*HID_C,  HID_C);
    cvt(14, pbnp + 3*HID_C,  HID_C);
    cvt(2,  plab,                   N_NODES * OUT_C);
    cvt(3,  plab + N_NODES * OUT_C, N_NODES * OUT_C);

    const int EB = (N_EDGES + 255) / 256;
    deg_count<<<EB, 256, 0, stream>>>(ei, d_in[4]);
    dinv_kernel<<<(N_NODES + 255) / 256, 256, 0, stream>>>();
    chunk_sum<<<N_CHUNK, 256, 0, stream>>>();
    chunk_scan<<<1, 1, 0, stream>>>();
    local_scan<<<N_CHUNK, 256, 0, stream>>>();
    fill_kernel<<<EB, 256, 0, stream>>>(ei, d_in[4]);

    const int MB64 = (N_NODES + 63) / 64;
    float* outf = (float*)d_out;   // fp32 output buffer: out | y_hat | y_hat2

    // layer 0
    sgemm<<<dim3(MB64, HID_C / 64), 256, 0, stream>>>(px, pw0, pA, N_NODES, HID_C, IN_C);
    prop256<<<N_NODES, 256, 0, stream>>>(pA, pB, pbias);
    bn_stats<<<256, 256, 0, stream>>>(pB, 0);
    bn_final<<<1, 256, 0, stream>>>(0);
    bn_apply<<<(N_NODES * HID_C + 255) / 256, 256, 0, stream>>>(pB, 0);

    // layer 1
    sgemm<<<dim3(MB64, HID_C / 64), 256, 0, stream>>>(pB, pw1, pA, N_NODES, HID_C, HID_C);
    prop256<<<N_NODES, 256, 0, stream>>>(pA, pB, pbias + HID_C);
    bn_stats<<<256, 256, 0, stream>>>(pB, 1);
    bn_final<<<1, 256, 0, stream>>>(1);
    bn_apply<<<(N_NODES * HID_C + 255) / 256, 256, 0, stream>>>(pB, 1);

    // layer 2 -> outf[0 : N*40]
    sgemm<<<dim3(MB64, 1), 256, 0, stream>>>(pB, pw2, p40a, N_NODES, OUT_C, HID_C);
    prop40<<<N_NODES, 64, 0, stream>>>(p40a, outf, pbias + 2 * HID_C);

    // label propagation x3 (two matrices) -> outf[2M:4M], outf[4M:6M]
    prop40<<<N_NODES, 64, 0, stream>>>(plab,  p40a, nullptr);
    prop40<<<N_NODES, 64, 0, stream>>>(p40a,  p40b, nullptr);
    prop40<<<N_NODES, 64, 0, stream>>>(p40b,  outf + (size_t)N_NODES * OUT_C, nullptr);

    prop40<<<N_NODES, 64, 0, stream>>>(plab + N_NODES * OUT_C, p40a, nullptr);
    prop40<<<N_NODES, 64, 0, stream>>>(p40a,  p40b, nullptr);
    prop40<<<N_NODES, 64, 0, stream>>>(p40b,  outf + 2 * (size_t)N_NODES * OUT_C, nullptr);
}

// Round 5
// 1394.305 us; speedup vs baseline: 1.3302x; 1.3302x over previous
//
#include <hip/hip_runtime.h>

#define N_NODES 50000
#define N_EDGES 800000
#define IN_C    512
#define HID_C   256
#define OUT_C   40
#define BN_EPS  1e-5f
#define N_CHUNK ((N_NODES + 255) / 256)   // 196

typedef _Float16 half8 __attribute__((ext_vector_type(8)));
typedef float    f32x4 __attribute__((ext_vector_type(4)));

// ---------------- static device buffers ----------------
__device__ float g_A   [N_NODES * HID_C];   // gemm out
__device__ float g_B   [N_NODES * HID_C];   // prop out (pre-BN-apply)
__device__ float g_40a [N_NODES * OUT_C];
__device__ float g_40b [N_NODES * OUT_C];
__device__ float g_40c [N_NODES * OUT_C];
__device__ float g_40d [N_NODES * OUT_C];
__device__ float g_deg [N_NODES];
__device__ float g_dinv[N_NODES];
__device__ int   g_cnt [N_NODES];
__device__ int   g_fill[N_NODES];
__device__ int   g_rowptr[N_NODES + 1];
__device__ int   g_colidx[N_EDGES];
__device__ float g_normv [N_EDGES];
__device__ float g_bnstat[4 * HID_C];       // sum0|ss0|sum1|ss1
__device__ float g_bnss  [4 * HID_C];       // scale0|shift0|scale1|shift1
__device__ int   g_csum[256];
__device__ int   g_cpre[256];

// ---------------- graph build (inputs: int32 edge_index, fp32 edge_weight) ---
__global__ void deg_count(const int* __restrict__ row, const float* __restrict__ w) {
    int e = blockIdx.x * blockDim.x + threadIdx.x;
    if (e < N_EDGES) {
        int r = row[e];
        atomicAdd(&g_deg[r], w[e]);
        atomicAdd(&g_cnt[r], 1);
    }
}

__global__ void dinv_kernel() {
    int i = blockIdx.x * blockDim.x + threadIdx.x;
    if (i < N_NODES) {
        float d = g_deg[i] + 1.0f;   // + self-loop weight 1
        g_dinv[i] = (d > 0.f) ? rsqrtf(fmaxf(d, 1e-12f)) : 0.f;
    }
}

__global__ __launch_bounds__(256) void chunk_sum() {
    __shared__ int sh[256];
    int i = blockIdx.x * 256 + threadIdx.x;
    sh[threadIdx.x] = (i < N_NODES) ? g_cnt[i] : 0;
    __syncthreads();
    for (int s = 128; s > 0; s >>= 1) {
        if (threadIdx.x < s) sh[threadIdx.x] += sh[threadIdx.x + s];
        __syncthreads();
    }
    if (threadIdx.x == 0) g_csum[blockIdx.x] = sh[0];
}
__global__ void chunk_scan() {
    int acc = 0;
    for (int b = 0; b < N_CHUNK; ++b) { g_cpre[b] = acc; acc += g_csum[b]; }
    g_rowptr[N_NODES] = acc;
}
__global__ __launch_bounds__(256) void local_scan() {
    __shared__ int woff[4];
    int t = threadIdx.x, lane = t & 63, wv = t >> 6;
    int i = blockIdx.x * 256 + t;
    int v = (i < N_NODES) ? g_cnt[i] : 0;
    int x = v;
    #pragma unroll
    for (int off = 1; off < 64; off <<= 1) {
        int y = __shfl_up(x, off);
        if (lane >= off) x += y;
    }
    if (lane == 63) woff[wv] = x;
    __syncthreads();
    if (t == 0) {
        int a = 0;
        #pragma unroll
        for (int w = 0; w < 4; ++w) { int tmp = woff[w]; woff[w] = a; a += tmp; }
    }
    __syncthreads();
    if (i < N_NODES) g_rowptr[i] = g_cpre[blockIdx.x] + woff[wv] + (x - v);
}

__global__ void fill_kernel(const int* __restrict__ row, const int* __restrict__ col,
                            const float* __restrict__ w) {
    int e = blockIdx.x * blockDim.x + threadIdx.x;
    if (e < N_EDGES) {
        int r = row[e], c = col[e];
        int pos = g_rowptr[r] + atomicAdd(&g_fill[r], 1);
        g_colidx[pos] = c;
        g_normv[pos]  = g_dinv[r] * w[e] * g_dinv[c];
    }
}

// ---------------- MFMA fp16 GEMM: C[M,N] = A[M,K] @ B[K,N] -------------------
// 64x64 tile, BK=32, 256 thr = 4 waves. Optional fused BN(scale,shift)+ReLU on
// A-load (indexed by k = channel). v_mfma_f32_16x16x32_f16:
//   A-frag: lane L holds A[m=L&15][k=(L>>4)*8+j]; B-frag symmetric (n=L&15);
//   C/D:    acc[r] = C[row=(L>>4)*4+r][col=L&15]  (m89-verified mapping).
__global__ __launch_bounds__(256) void gemm_mfma(const float* __restrict__ A,
                                                 const float* __restrict__ B,
                                                 float* __restrict__ C,
                                                 int M, int N, int K,
                                                 const float* __restrict__ bnscale,
                                                 const float* __restrict__ bnshift) {
    __shared__ _Float16 As[64][40];   // rows padded to 40 halfs = 80 B (16B-mult)
    __shared__ _Float16 Bs[64][40];   // transposed: Bs[n][k]
    int tid  = threadIdx.x;
    int wv   = tid >> 6, lane = tid & 63;
    int quad = lane >> 4, l16 = lane & 15;
    int n0 = blockIdx.x * 64, m0 = blockIdx.y * 64;   // n fastest -> A L2 reuse
    f32x4 acc[4];
    #pragma unroll
    for (int s = 0; s < 4; ++s) acc[s] = (f32x4){0.f, 0.f, 0.f, 0.f};
    int arow = tid >> 2;          // 0..63
    int acol = (tid & 3) * 8;     // 0,8,16,24
    int bk   = tid >> 3;          // 0..31
    int bn   = (tid & 7) * 8;     // 0..56

    for (int k0 = 0; k0 < K; k0 += 32) {
        // stage A (with optional BN+ReLU)
        int gm = m0 + arow;
        float av[8];
        if (gm < M) {
            float4 a0 = *(const float4*)(A + (size_t)gm * K + k0 + acol);
            float4 a1 = *(const float4*)(A + (size_t)gm * K + k0 + acol + 4);
            av[0] = a0.x; av[1] = a0.y; av[2] = a0.z; av[3] = a0.w;
            av[4] = a1.x; av[5] = a1.y; av[6] = a1.z; av[7] = a1.w;
        } else {
            #pragma unroll
            for (int j = 0; j < 8; ++j) av[j] = 0.f;
        }
        if (bnscale) {
            #pragma unroll
            for (int j = 0; j < 8; ++j) {
                int k = k0 + acol + j;
                av[j] = fmaxf(av[j] * bnscale[k] + bnshift[k], 0.f);
            }
        }
        #pragma unroll
        for (int j = 0; j < 8; ++j) As[arow][acol + j] = (_Float16)av[j];
        // stage B transposed
        const float* bp = B + (size_t)(k0 + bk) * N;
        #pragma unroll
        for (int j = 0; j < 8; ++j) {
            int n = bn + j;
            float v = (n0 + n < N) ? bp[n0 + n] : 0.f;
            Bs[n][bk] = (_Float16)v;
        }
        __syncthreads();
        half8 af = *(const half8*)&As[wv * 16 + l16][quad * 8];
        #pragma unroll
        for (int s = 0; s < 4; ++s) {
            half8 bf = *(const half8*)&Bs[s * 16 + l16][quad * 8];
            acc[s] = __builtin_amdgcn_mfma_f32_16x16x32_f16(af, bf, acc[s], 0, 0, 0);
        }
        __syncthreads();
    }
    #pragma unroll
    for (int s = 0; s < 4; ++s) {
        int n = n0 + s * 16 + l16;
        if (n < N) {
            #pragma unroll
            for (int r = 0; r < 4; ++r) {
                int m = m0 + wv * 16 + quad * 4 + r;
                if (m < M) C[(size_t)m * N + n] = acc[s][r];
            }
        }
    }
}

// ---------------- propagation: wave-per-node, float4 per lane ----------------
__global__ __launch_bounds__(256) void prop256v2(const float* __restrict__ h,
                                                 float* __restrict__ out,
                                                 const float* __restrict__ bias) {
    int wv = threadIdx.x >> 6, lane = threadIdx.x & 63;
    int i = blockIdx.x * 4 + wv;               // grid = 12500 exact
    const float4* hv = (const float4*)h;
    float di = g_dinv[i];
    float4 r = hv[(size_t)i * 64 + lane];
    float d2 = di * di;
    float4 acc = make_float4(d2 * r.x, d2 * r.y, d2 * r.z, d2 * r.w);
    int s = g_rowptr[i], e = g_rowptr[i + 1];
    for (int k = s; k < e; ++k) {
        int   j  = g_colidx[k];
        float nv = g_normv[k];
        float4 v = hv[(size_t)j * 64 + lane];
        acc.x += nv * v.x; acc.y += nv * v.y; acc.z += nv * v.z; acc.w += nv * v.w;
    }
    float4 b = ((const float4*)bias)[lane];
    acc.x += b.x; acc.y += b.y; acc.z += b.z; acc.w += b.w;
    ((float4*)out)[(size_t)i * 64 + lane] = acc;
}

// 40-wide single-matrix propagation (GCN output), 4 nodes/block
__global__ __launch_bounds__(256) void prop40v2(const float* __restrict__ h,
                                                float* __restrict__ out,
                                                const float* __restrict__ bias) {
    int wv = threadIdx.x >> 6, lane = threadIdx.x & 63;
    if (lane >= OUT_C) return;
    int i = blockIdx.x * 4 + wv;
    float di = g_dinv[i];
    float acc = di * di * h[(size_t)i * OUT_C + lane];
    int s = g_rowptr[i], e = g_rowptr[i + 1];
    for (int k = s; k < e; ++k)
        acc += g_normv[k] * h[(size_t)g_colidx[k] * OUT_C + lane];
    out[(size_t)i * OUT_C + lane] = acc + bias[lane];
}

// paired label propagation: both matrices in one edge traversal
__global__ __launch_bounds__(256) void prop40pair(const float* __restrict__ y1,
                                                  const float* __restrict__ y2,
                                                  float* __restrict__ o1,
                                                  float* __restrict__ o2) {
    int wv = threadIdx.x >> 6, lane = threadIdx.x & 63;
    if (lane >= OUT_C) return;
    int i = blockIdx.x * 4 + wv;
    float di = g_dinv[i];
    float d2 = di * di;
    float a1 = d2 * y1[(size_t)i * OUT_C + lane];
    float a2 = d2 * y2[(size_t)i * OUT_C + lane];
    int s = g_rowptr[i], e = g_rowptr[i + 1];
    for (int k = s; k < e; ++k) {
        int   j  = g_colidx[k];
        float nv = g_normv[k];
        a1 += nv * y1[(size_t)j * OUT_C + lane];
        a2 += nv * y2[(size_t)j * OUT_C + lane];
    }
    o1[(size_t)i * OUT_C + lane] = a1;
    o2[(size_t)i * OUT_C + lane] = a2;
}

// ---------------- batchnorm stats ----------------
__global__ __launch_bounds__(256) void bn_stats(const float* __restrict__ h, int layer) {
    int c = threadIdx.x;
    float s = 0.f, ss = 0.f;
    for (int i = blockIdx.x; i < N_NODES; i += gridDim.x) {
        float v = h[(size_t)i * HID_C + c];
        s += v; ss += v * v;
    }
    atomicAdd(&g_bnstat[layer * 512 + c], s);
    atomicAdd(&g_bnstat[layer * 512 + 256 + c], ss);
}

__global__ void bn_final(int layer, const float* __restrict__ gamma,
                         const float* __restrict__ beta) {
    int c = threadIdx.x;
    float sum = g_bnstat[layer * 512 + c];
    float ss  = g_bnstat[layer * 512 + 256 + c];
    float mu  = sum / (float)N_NODES;
    float var = fmaxf(ss / (float)N_NODES - mu * mu, 0.f);
    float scale = gamma[c] * rsqrtf(var + BN_EPS);
    g_bnss[layer * 512 + c]       = scale;
    g_bnss[layer * 512 + 256 + c] = beta[c] - mu * scale;
}

// ---------------- host ----------------
template <typename T>
static T* symaddr(const void* sym) {
    void* p = nullptr;
    (void)hipGetSymbolAddress(&p, sym);
    return (T*)p;
}

extern "C" void kernel_launch(void* const* d_in, const int* in_sizes, int n_in,
                              void* d_out, int out_size, void* d_ws, size_t ws_size,
                              hipStream_t stream) {
    const float* x    = (const float*)d_in[0];
    const int*   ei   = (const int*)d_in[1];          // row=ei[0:E], col=ei[E:2E]
    const float* lab1 = (const float*)d_in[2];
    const float* lab2 = (const float*)d_in[3];
    const float* ew   = (const float*)d_in[4];
    const float* W0   = (const float*)d_in[5];
    const float* b0   = (const float*)d_in[6];
    const float* W1   = (const float*)d_in[7];
    const float* b1   = (const float*)d_in[8];
    const float* W2   = (const float*)d_in[9];
    const float* b2   = (const float*)d_in[10];
    const float* gg0  = (const float*)d_in[11];
    const float* be0  = (const float*)d_in[12];
    const float* gg1  = (const float*)d_in[13];
    const float* be1  = (const float*)d_in[14];

    float* pA   = symaddr<float>(HIP_SYMBOL(g_A));
    float* pB   = symaddr<float>(HIP_SYMBOL(g_B));
    float* p40a = symaddr<float>(HIP_SYMBOL(g_40a));
    float* p40b = symaddr<float>(HIP_SYMBOL(g_40b));
    float* p40c = symaddr<float>(HIP_SYMBOL(g_40c));
    float* p40d = symaddr<float>(HIP_SYMBOL(g_40d));
    float* pdeg = symaddr<float>(HIP_SYMBOL(g_deg));
    int*   pcnt = symaddr<int>(HIP_SYMBOL(g_cnt));
    int*   pfil = symaddr<int>(HIP_SYMBOL(g_fill));
    float* pbst = symaddr<float>(HIP_SYMBOL(g_bnstat));
    float* pbss = symaddr<float>(HIP_SYMBOL(g_bnss));

    hipMemsetAsync(pdeg, 0, N_NODES * sizeof(float), stream);
    hipMemsetAsync(pcnt, 0, N_NODES * sizeof(int),   stream);
    hipMemsetAsync(pfil, 0, N_NODES * sizeof(int),   stream);
    hipMemsetAsync(pbst, 0, 4 * HID_C * sizeof(float), stream);

    // CSR build (self loops folded analytically via dinv^2)
    const int EB = (N_EDGES + 255) / 256;
    deg_count<<<EB, 256, 0, stream>>>(ei, ew);
    dinv_kernel<<<(N_NODES + 255) / 256, 256, 0, stream>>>();
    chunk_sum<<<N_CHUNK, 256, 0, stream>>>();
    chunk_scan<<<1, 1, 0, stream>>>();
    local_scan<<<N_CHUNK, 256, 0, stream>>>();
    fill_kernel<<<EB, 256, 0, stream>>>(ei, ei + N_EDGES, ew);

    const int GM = (N_NODES + 63) / 64;   // 782
    const int PB = N_NODES / 4;           // 12500
    float* outf = (float*)d_out;          // fp32: out | y_hat | y_hat2

    // layer 0: prop(x@W0)+b0 -> stats
    gemm_mfma<<<dim3(HID_C / 64, GM), 256, 0, stream>>>(x, W0, pA, N_NODES, HID_C, IN_C,
                                                        nullptr, nullptr);
    prop256v2<<<PB, 256, 0, stream>>>(pA, pB, b0);
    bn_stats<<<256, 256, 0, stream>>>(pB, 0);
    bn_final<<<1, 256, 0, stream>>>(0, gg0, be0);

    // layer 1: A-load applies BN0+ReLU
    gemm_mfma<<<dim3(HID_C / 64, GM), 256, 0, stream>>>(pB, W1, pA, N_NODES, HID_C, HID_C,
                                                        pbss, pbss + 256);
    prop256v2<<<PB, 256, 0, stream>>>(pA, pB, b1);
    bn_stats<<<256, 256, 0, stream>>>(pB, 1);
    bn_final<<<1, 256, 0, stream>>>(1, gg1, be1);

    // layer 2: A-load applies BN1+ReLU; out = prop(h@W2)+b2 -> outf[0:N*40]
    gemm_mfma<<<dim3(1, GM), 256, 0, stream>>>(pB, W2, p40a, N_NODES, OUT_C, HID_C,
                                               pbss + 512, pbss + 768);
    prop40v2<<<PB, 256, 0, stream>>>(p40a, outf, b2);

    // label propagation x3, both matrices per pass
    prop40pair<<<PB, 256, 0, stream>>>(lab1, lab2, p40a, p40b);
    prop40pair<<<PB, 256, 0, stream>>>(p40a, p40b, p40c, p40d);
    prop40pair<<<PB, 256, 0, stream>>>(p40c, p40d,
                                       outf + (size_t)N_NODES * OUT_C,
                                       outf + 2 * (size_t)N_NODES * OUT_C);
}

// Round 6
// 1265.349 us; speedup vs baseline: 1.4658x; 1.1019x over previous
//
#include <hip/hip_runtime.h>

#define N_NODES 50000
#define N_PAD   50048            // 782*64 / 391*128 row padding for fp16 A-buffers
#define N_EDGES 800000
#define IN_C    512
#define HID_C   256
#define OUT_C   40
#define BN_EPS  1e-5f
#define N_CHUNK ((N_NODES + 255) / 256)   // 196

typedef _Float16 half8  __attribute__((ext_vector_type(8)));
typedef _Float16 half4v __attribute__((ext_vector_type(4)));
typedef float    f32x16 __attribute__((ext_vector_type(16)));

// ---------------- static device buffers ----------------
__device__ _Float16 g_xh [(size_t)N_PAD * IN_C];    // x as fp16 (padded rows: stale, never stored)
__device__ _Float16 g_h16[(size_t)N_PAD * HID_C];   // BN+ReLU'd hidden, fp16
__device__ _Float16 g_w0t[HID_C * IN_C];            // W0^T  [256][512]
__device__ _Float16 g_w1t[HID_C * HID_C];           // W1^T  [256][256]
__device__ _Float16 g_w2t[64 * HID_C];              // W2^T padded [64][256]
__device__ float g_A   [N_NODES * HID_C];   // gemm out
__device__ float g_B   [N_NODES * HID_C];   // prop out (pre-BN)
__device__ float g_40a [N_NODES * OUT_C];
__device__ float g_40b [N_NODES * OUT_C];
__device__ float g_40c [N_NODES * OUT_C];
__device__ float g_40d [N_NODES * OUT_C];
__device__ float g_deg [N_NODES];
__device__ float g_dinv[N_NODES];
__device__ int   g_cnt [N_NODES];
__device__ int   g_fill[N_NODES];
__device__ int   g_rowptr[N_NODES + 1];
__device__ int   g_colidx[N_EDGES];
__device__ float g_normv [N_EDGES];
__device__ float g_bnstat[4 * HID_C];       // sum0|ss0|sum1|ss1
__device__ float g_bnss  [4 * HID_C];       // scale0|shift0|scale1|shift1
__device__ int   g_csum[256];
__device__ int   g_cpre[256];

// ---------------- graph build ----------------
__global__ void deg_count(const int* __restrict__ row, const float* __restrict__ w) {
    int e = blockIdx.x * blockDim.x + threadIdx.x;
    if (e < N_EDGES) {
        int r = row[e];
        atomicAdd(&g_deg[r], w[e]);
        atomicAdd(&g_cnt[r], 1);
    }
}

__global__ void dinv_kernel() {
    int i = blockIdx.x * blockDim.x + threadIdx.x;
    if (i < N_NODES) {
        float d = g_deg[i] + 1.0f;   // + self-loop weight 1
        g_dinv[i] = (d > 0.f) ? rsqrtf(fmaxf(d, 1e-12f)) : 0.f;
    }
}

__global__ __launch_bounds__(256) void chunk_sum() {
    __shared__ int sh[256];
    int i = blockIdx.x * 256 + threadIdx.x;
    sh[threadIdx.x] = (i < N_NODES) ? g_cnt[i] : 0;
    __syncthreads();
    for (int s = 128; s > 0; s >>= 1) {
        if (threadIdx.x < s) sh[threadIdx.x] += sh[threadIdx.x + s];
        __syncthreads();
    }
    if (threadIdx.x == 0) g_csum[blockIdx.x] = sh[0];
}
__global__ void chunk_scan() {
    int acc = 0;
    for (int b = 0; b < N_CHUNK; ++b) { g_cpre[b] = acc; acc += g_csum[b]; }
    g_rowptr[N_NODES] = acc;
}
__global__ __launch_bounds__(256) void local_scan() {
    __shared__ int woff[4];
    int t = threadIdx.x, lane = t & 63, wv = t >> 6;
    int i = blockIdx.x * 256 + t;
    int v = (i < N_NODES) ? g_cnt[i] : 0;
    int x = v;
    #pragma unroll
    for (int off = 1; off < 64; off <<= 1) {
        int y = __shfl_up(x, off);
        if (lane >= off) x += y;
    }
    if (lane == 63) woff[wv] = x;
    __syncthreads();
    if (t == 0) {
        int a = 0;
        #pragma unroll
        for (int w = 0; w < 4; ++w) { int tmp = woff[w]; woff[w] = a; a += tmp; }
    }
    __syncthreads();
    if (i < N_NODES) g_rowptr[i] = g_cpre[blockIdx.x] + woff[wv] + (x - v);
}

__global__ void fill_kernel(const int* __restrict__ row, const int* __restrict__ col,
                            const float* __restrict__ w) {
    int e = blockIdx.x * blockDim.x + threadIdx.x;
    if (e < N_EDGES) {
        int r = row[e], c = col[e];
        int pos = g_rowptr[r] + atomicAdd(&g_fill[r], 1);
        g_colidx[pos] = c;
        g_normv[pos]  = g_dinv[r] * w[e] * g_dinv[c];
    }
}

// ---------------- conversions ----------------
__global__ void cvt_f16(const float* __restrict__ in, _Float16* __restrict__ out, int n4) {
    int i = blockIdx.x * blockDim.x + threadIdx.x;
    if (i < n4) {
        float4 v = ((const float4*)in)[i];
        half4v o; o.x = (_Float16)v.x; o.y = (_Float16)v.y; o.z = (_Float16)v.z; o.w = (_Float16)v.w;
        ((half4v*)out)[i] = o;
    }
}

// W [K][N] fp32 -> WT [Npad][K] fp16 (zero-pad cols >= N)
__global__ void wtrans(const float* __restrict__ W, _Float16* __restrict__ WT,
                       int K, int N, int Npad) {
    int idx = blockIdx.x * blockDim.x + threadIdx.x;
    if (idx >= Npad * K) return;
    int n = idx / K, k = idx - n * K;
    WT[idx] = (_Float16)((n < N) ? W[(size_t)k * N + n] : 0.f);
}

// BN scale/shift + ReLU + fp16 cast: h[50000][256] fp32 -> out fp16
__global__ __launch_bounds__(256) void bn_apply_cvt(const float* __restrict__ h,
                                                    _Float16* __restrict__ out,
                                                    const float* __restrict__ scale,
                                                    const float* __restrict__ shift) {
    int i = blockIdx.x * blockDim.x + threadIdx.x;   // float4-group index
    if (i >= N_NODES * (HID_C / 4)) return;
    int c = (i & 63) * 4;
    float4 v = ((const float4*)h)[i];
    half4v o;
    o.x = (_Float16)fmaxf(v.x * scale[c + 0] + shift[c + 0], 0.f);
    o.y = (_Float16)fmaxf(v.y * scale[c + 1] + shift[c + 1], 0.f);
    o.z = (_Float16)fmaxf(v.z * scale[c + 2] + shift[c + 2], 0.f);
    o.w = (_Float16)fmaxf(v.w * scale[c + 3] + shift[c + 3], 0.f);
    ((half4v*)out)[i] = o;
}

// ---------------- register-only MFMA GEMM (no LDS, no barriers) --------------
// v_mfma_f32_32x32x16_f16. A [M][K] fp16 row-major, BT [N][K] fp16 (B^T).
// A-frag:  lane holds A[m = lane&31][k = (lane>>5)*8 + j]  -> one b128 load.
// B-frag:  symmetric from BT.
// C/D:     col = lane&31, row = (reg&3) + 8*(reg>>2) + 4*(lane>>5)  [m74/m101].
// gemm_h: N=256. Block 256thr = 4 waves: wm=w>>1 (32-row groups), wn=w&1
// (128-col halves). Grid x = M_pad/64. C fp32 [M][256].
__global__ __launch_bounds__(256) void gemm_h(const _Float16* __restrict__ A,
                                              const _Float16* __restrict__ BT,
                                              float* __restrict__ C,
                                              int M, int K) {
    int w = threadIdx.x >> 6, lane = threadIdx.x & 63;
    int wm = w >> 1, wn = w & 1;
    int m0 = blockIdx.x * 64 + wm * 32;
    int nb = wn * 128;
    int l31 = lane & 31, kh = (lane >> 5) * 8;
    const _Float16* ap  = A  + (size_t)(m0 + l31) * K + kh;
    const _Float16* bp  = BT + (size_t)(nb + l31) * K + kh;
    f32x16 acc[4];
    #pragma unroll
    for (int nt = 0; nt < 4; ++nt)
        #pragma unroll
        for (int s = 0; s < 16; ++s) acc[nt][s] = 0.f;

    for (int k = 0; k < K; k += 16) {
        half8 af = *(const half8*)(ap + k);
        #pragma unroll
        for (int nt = 0; nt < 4; ++nt) {
            half8 bf = *(const half8*)(bp + (size_t)nt * 32 * K + k);
            acc[nt] = __builtin_amdgcn_mfma_f32_32x32x16_f16(af, bf, acc[nt], 0, 0, 0);
        }
    }
    int mrow = m0 + 4 * (lane >> 5);
    #pragma unroll
    for (int nt = 0; nt < 4; ++nt) {
        int n = nb + nt * 32 + l31;
        #pragma unroll
        for (int r = 0; r < 16; ++r) {
            int m = mrow + (r & 3) + 8 * (r >> 2);
            if (m < M) C[(size_t)m * HID_C + n] = acc[nt][r];
        }
    }
}

// gemm_out: K=256, N=40 (BT padded to 64 rows). Block 4 waves x 32 rows = 128
// rows, each wave covers cols 0..63 (2 n-subtiles). C fp32 [M][40].
__global__ __launch_bounds__(256) void gemm_out(const _Float16* __restrict__ A,
                                                const _Float16* __restrict__ BT,
                                                float* __restrict__ C, int M) {
    const int K = HID_C;
    int w = threadIdx.x >> 6, lane = threadIdx.x & 63;
    int m0 = blockIdx.x * 128 + w * 32;
    int l31 = lane & 31, kh = (lane >> 5) * 8;
    const _Float16* ap = A  + (size_t)(m0 + l31) * K + kh;
    const _Float16* bp = BT + (size_t)l31 * K + kh;
    f32x16 acc[2];
    #pragma unroll
    for (int nt = 0; nt < 2; ++nt)
        #pragma unroll
        for (int s = 0; s < 16; ++s) acc[nt][s] = 0.f;

    for (int k = 0; k < K; k += 16) {
        half8 af = *(const half8*)(ap + k);
        #pragma unroll
        for (int nt = 0; nt < 2; ++nt) {
            half8 bf = *(const half8*)(bp + (size_t)nt * 32 * K + k);
            acc[nt] = __builtin_amdgcn_mfma_f32_32x32x16_f16(af, bf, acc[nt], 0, 0, 0);
        }
    }
    int mrow = m0 + 4 * (lane >> 5);
    #pragma unroll
    for (int nt = 0; nt < 2; ++nt) {
        int n = nt * 32 + l31;
        if (n < OUT_C) {
            #pragma unroll
            for (int r = 0; r < 16; ++r) {
                int m = mrow + (r & 3) + 8 * (r >> 2);
                if (m < M) C[(size_t)m * OUT_C + n] = acc[nt][r];
            }
        }
    }
}

// ---------------- propagation: wave-per-node, float4 per lane ----------------
__global__ __launch_bounds__(256) void prop256v2(const float* __restrict__ h,
                                                 float* __restrict__ out,
                                                 const float* __restrict__ bias) {
    int wv = threadIdx.x >> 6, lane = threadIdx.x & 63;
    int i = blockIdx.x * 4 + wv;               // grid = 12500 exact
    const float4* hv = (const float4*)h;
    float di = g_dinv[i];
    float4 r = hv[(size_t)i * 64 + lane];
    float d2 = di * di;
    float4 acc = make_float4(d2 * r.x, d2 * r.y, d2 * r.z, d2 * r.w);
    int s = g_rowptr[i], e = g_rowptr[i + 1];
    for (int k = s; k < e; ++k) {
        int   j  = g_colidx[k];
        float nv = g_normv[k];
        float4 v = hv[(size_t)j * 64 + lane];
        acc.x += nv * v.x; acc.y += nv * v.y; acc.z += nv * v.z; acc.w += nv * v.w;
    }
    float4 b = ((const float4*)bias)[lane];
    acc.x += b.x; acc.y += b.y; acc.z += b.z; acc.w += b.w;
    ((float4*)out)[(size_t)i * 64 + lane] = acc;
}

__global__ __launch_bounds__(256) void prop40v2(const float* __restrict__ h,
                                                float* __restrict__ out,
                                                const float* __restrict__ bias) {
    int wv = threadIdx.x >> 6, lane = threadIdx.x & 63;
    if (lane >= OUT_C) return;
    int i = blockIdx.x * 4 + wv;
    float di = g_dinv[i];
    float acc = di * di * h[(size_t)i * OUT_C + lane];
    int s = g_rowptr[i], e = g_rowptr[i + 1];
    for (int k = s; k < e; ++k)
        acc += g_normv[k] * h[(size_t)g_colidx[k] * OUT_C + lane];
    out[(size_t)i * OUT_C + lane] = acc + bias[lane];
}

__global__ __launch_bounds__(256) void prop40pair(const float* __restrict__ y1,
                                                  const float* __restrict__ y2,
                                                  float* __restrict__ o1,
                                                  float* __restrict__ o2) {
    int wv = threadIdx.x >> 6, lane = threadIdx.x & 63;
    if (lane >= OUT_C) return;
    int i = blockIdx.x * 4 + wv;
    float di = g_dinv[i];
    float d2 = di * di;
    float a1 = d2 * y1[(size_t)i * OUT_C + lane];
    float a2 = d2 * y2[(size_t)i * OUT_C + lane];
    int s = g_rowptr[i], e = g_rowptr[i + 1];
    for (int k = s; k < e; ++k) {
        int   j  = g_colidx[k];
        float nv = g_normv[k];
        a1 += nv * y1[(size_t)j * OUT_C + lane];
        a2 += nv * y2[(size_t)j * OUT_C + lane];
    }
    o1[(size_t)i * OUT_C + lane] = a1;
    o2[(size_t)i * OUT_C + lane] = a2;
}

// ---------------- batchnorm stats ----------------
__global__ __launch_bounds__(256) void bn_stats(const float* __restrict__ h, int layer) {
    int c = threadIdx.x;
    float s = 0.f, ss = 0.f;
    for (int i = blockIdx.x; i < N_NODES; i += gridDim.x) {
        float v = h[(size_t)i * HID_C + c];
        s += v; ss += v * v;
    }
    atomicAdd(&g_bnstat[layer * 512 + c], s);
    atomicAdd(&g_bnstat[layer * 512 + 256 + c], ss);
}

__global__ void bn_final(int layer, const float* __restrict__ gamma,
                         const float* __restrict__ beta) {
    int c = threadIdx.x;
    float sum = g_bnstat[layer * 512 + c];
    float ss  = g_bnstat[layer * 512 + 256 + c];
    float mu  = sum / (float)N_NODES;
    float var = fmaxf(ss / (float)N_NODES - mu * mu, 0.f);
    float scale = gamma[c] * rsqrtf(var + BN_EPS);
    g_bnss[layer * 512 + c]       = scale;
    g_bnss[layer * 512 + 256 + c] = beta[c] - mu * scale;
}

// ---------------- host ----------------
template <typename T>
static T* symaddr(const void* sym) {
    void* p = nullptr;
    (void)hipGetSymbolAddress(&p, sym);
    return (T*)p;
}

extern "C" void kernel_launch(void* const* d_in, const int* in_sizes, int n_in,
                              void* d_out, int out_size, void* d_ws, size_t ws_size,
                              hipStream_t stream) {
    const float* x    = (const float*)d_in[0];
    const int*   ei   = (const int*)d_in[1];
    const float* lab1 = (const float*)d_in[2];
    const float* lab2 = (const float*)d_in[3];
    const float* ew   = (const float*)d_in[4];
    const float* W0   = (const float*)d_in[5];
    const float* b0   = (const float*)d_in[6];
    const float* W1   = (const float*)d_in[7];
    const float* b1   = (const float*)d_in[8];
    const float* W2   = (const float*)d_in[9];
    const float* b2   = (const float*)d_in[10];
    const float* gg0  = (const float*)d_in[11];
    const float* be0  = (const float*)d_in[12];
    const float* gg1  = (const float*)d_in[13];
    const float* be1  = (const float*)d_in[14];

    _Float16* pxh  = symaddr<_Float16>(HIP_SYMBOL(g_xh));
    _Float16* ph16 = symaddr<_Float16>(HIP_SYMBOL(g_h16));
    _Float16* pw0t = symaddr<_Float16>(HIP_SYMBOL(g_w0t));
    _Float16* pw1t = symaddr<_Float16>(HIP_SYMBOL(g_w1t));
    _Float16* pw2t = symaddr<_Float16>(HIP_SYMBOL(g_w2t));
    float* pA   = symaddr<float>(HIP_SYMBOL(g_A));
    float* pB   = symaddr<float>(HIP_SYMBOL(g_B));
    float* p40a = symaddr<float>(HIP_SYMBOL(g_40a));
    float* p40b = symaddr<float>(HIP_SYMBOL(g_40b));
    float* p40c = symaddr<float>(HIP_SYMBOL(g_40c));
    float* p40d = symaddr<float>(HIP_SYMBOL(g_40d));
    float* pdeg = symaddr<float>(HIP_SYMBOL(g_deg));
    int*   pcnt = symaddr<int>(HIP_SYMBOL(g_cnt));
    int*   pfil = symaddr<int>(HIP_SYMBOL(g_fill));
    float* pbst = symaddr<float>(HIP_SYMBOL(g_bnstat));
    float* pbss = symaddr<float>(HIP_SYMBOL(g_bnss));

    hipMemsetAsync(pdeg, 0, N_NODES * sizeof(float), stream);
    hipMemsetAsync(pcnt, 0, N_NODES * sizeof(int),   stream);
    hipMemsetAsync(pfil, 0, N_NODES * sizeof(int),   stream);
    hipMemsetAsync(pbst, 0, 4 * HID_C * sizeof(float), stream);

    // CSR build
    const int EB = (N_EDGES + 255) / 256;
    deg_count<<<EB, 256, 0, stream>>>(ei, ew);
    dinv_kernel<<<(N_NODES + 255) / 256, 256, 0, stream>>>();
    chunk_sum<<<N_CHUNK, 256, 0, stream>>>();
    chunk_scan<<<1, 1, 0, stream>>>();
    local_scan<<<N_CHUNK, 256, 0, stream>>>();
    fill_kernel<<<EB, 256, 0, stream>>>(ei, ei + N_EDGES, ew);

    // fp16 conversions (x, weights transposed)
    cvt_f16<<<(N_NODES * IN_C / 4 + 255) / 256, 256, 0, stream>>>(x, pxh, N_NODES * IN_C / 4);
    wtrans<<<(HID_C * IN_C + 255) / 256, 256, 0, stream>>>(W0, pw0t, IN_C, HID_C, HID_C);
    wtrans<<<(HID_C * HID_C + 255) / 256, 256, 0, stream>>>(W1, pw1t, HID_C, HID_C, HID_C);
    wtrans<<<(64 * HID_C + 255) / 256, 256, 0, stream>>>(W2, pw2t, HID_C, OUT_C, 64);

    const int GB  = N_PAD / 64;     // 782
    const int PB  = N_NODES / 4;    // 12500
    const int CB  = (N_NODES * 64 + 255) / 256;   // bn_apply_cvt blocks (float4 groups)
    float* outf = (float*)d_out;    // fp32: out | y_hat | y_hat2

    // layer 0
    gemm_h<<<GB, 256, 0, stream>>>(pxh, pw0t, pA, N_NODES, IN_C);
    prop256v2<<<PB, 256, 0, stream>>>(pA, pB, b0);
    bn_stats<<<256, 256, 0, stream>>>(pB, 0);
    bn_final<<<1, 256, 0, stream>>>(0, gg0, be0);
    bn_apply_cvt<<<CB, 256, 0, stream>>>(pB, ph16, pbss, pbss + 256);

    // layer 1
    gemm_h<<<GB, 256, 0, stream>>>(ph16, pw1t, pA, N_NODES, HID_C);
    prop256v2<<<PB, 256, 0, stream>>>(pA, pB, b1);
    bn_stats<<<256, 256, 0, stream>>>(pB, 1);
    bn_final<<<1, 256, 0, stream>>>(1, gg1, be1);
    bn_apply_cvt<<<CB, 256, 0, stream>>>(pB, ph16, pbss + 512, pbss + 768);

    // layer 2
    gemm_out<<<N_PAD / 128, 256, 0, stream>>>(ph16, pw2t, p40a, N_NODES);
    prop40v2<<<PB, 256, 0, stream>>>(p40a, outf, b2);

    // label propagation x3, both matrices per pass
    prop40pair<<<PB, 256, 0, stream>>>(lab1, lab2, p40a, p40b);
    prop40pair<<<PB, 256, 0, stream>>>(p40a, p40b, p40c, p40d);
    prop40pair<<<PB, 256, 0, stream>>>(p40c, p40d,
                                       outf + (size_t)N_NODES * OUT_C,
                                       outf + 2 * (size_t)N_NODES * OUT_C);
}

// Round 7
// 1133.809 us; speedup vs baseline: 1.6358x; 1.1160x over previous
//
#include <hip/hip_runtime.h>

#define N_NODES 50000
#define N_PAD   50048            // 782*64 / 391*128 row padding
#define N_EDGES 800000
#define IN_C    512
#define HID_C   256
#define OUT_C   40
#define BN_EPS  1e-5f
#define N_CHUNK ((N_NODES + 255) / 256)   // 196

typedef _Float16 half2v __attribute__((ext_vector_type(2)));
typedef _Float16 half4v __attribute__((ext_vector_type(4)));
typedef _Float16 half8  __attribute__((ext_vector_type(8)));
typedef float    f32x16 __attribute__((ext_vector_type(16)));

// ---------------- static device buffers ----------------
__device__ _Float16 g_h16 [(size_t)N_PAD * HID_C];  // BN+ReLU'd hidden (fp16)
__device__ _Float16 g_Ah  [(size_t)N_PAD * HID_C];  // gemm out (fp16, gather source)
__device__ _Float16 g_o40h[(size_t)N_PAD * OUT_C];  // out-layer gemm (fp16)
__device__ _Float16 g_l80a[(size_t)N_NODES * 80];   // labels interleaved y1|y2 fp16
__device__ _Float16 g_l80b[(size_t)N_NODES * 80];
__device__ _Float16 g_w0t[HID_C * IN_C];            // W0^T [256][512]
__device__ _Float16 g_w1t[HID_C * HID_C];           // W1^T [256][256]
__device__ _Float16 g_w2t[64 * HID_C];              // W2^T padded [64][256]
__device__ float g_B   [(size_t)N_NODES * HID_C];   // prop out fp32 (BN stats source)
__device__ float g_deg [N_NODES];
__device__ float g_dinv[N_NODES];
__device__ int   g_cnt [N_NODES];
__device__ int   g_fill[N_NODES];
__device__ int   g_rowptr[N_NODES + 1];
__device__ int   g_colidx[N_EDGES];
__device__ float g_normv [N_EDGES];
__device__ float g_bnstat[4 * HID_C];               // sum0|ss0|sum1|ss1
__device__ float g_bnss  [4 * HID_C];               // scale0|shift0|scale1|shift1
__device__ int   g_csum[256];
__device__ int   g_cpre[256];

// ---------------- graph build ----------------
__global__ void deg_count(const int* __restrict__ row, const float* __restrict__ w) {
    int e = blockIdx.x * blockDim.x + threadIdx.x;
    if (e < N_EDGES) {
        int r = row[e];
        atomicAdd(&g_deg[r], w[e]);
        atomicAdd(&g_cnt[r], 1);
    }
}

__global__ void dinv_kernel() {
    int i = blockIdx.x * blockDim.x + threadIdx.x;
    if (i < N_NODES) {
        float d = g_deg[i] + 1.0f;   // + self-loop weight 1
        g_dinv[i] = (d > 0.f) ? rsqrtf(fmaxf(d, 1e-12f)) : 0.f;
    }
}

__global__ __launch_bounds__(256) void chunk_sum() {
    __shared__ int sh[256];
    int i = blockIdx.x * 256 + threadIdx.x;
    sh[threadIdx.x] = (i < N_NODES) ? g_cnt[i] : 0;
    __syncthreads();
    for (int s = 128; s > 0; s >>= 1) {
        if (threadIdx.x < s) sh[threadIdx.x] += sh[threadIdx.x + s];
        __syncthreads();
    }
    if (threadIdx.x == 0) g_csum[blockIdx.x] = sh[0];
}
__global__ void chunk_scan() {
    int acc = 0;
    for (int b = 0; b < N_CHUNK; ++b) { g_cpre[b] = acc; acc += g_csum[b]; }
    g_rowptr[N_NODES] = acc;
}
__global__ __launch_bounds__(256) void local_scan() {
    __shared__ int woff[4];
    int t = threadIdx.x, lane = t & 63, wv = t >> 6;
    int i = blockIdx.x * 256 + t;
    int v = (i < N_NODES) ? g_cnt[i] : 0;
    int x = v;
    #pragma unroll
    for (int off = 1; off < 64; off <<= 1) {
        int y = __shfl_up(x, off);
        if (lane >= off) x += y;
    }
    if (lane == 63) woff[wv] = x;
    __syncthreads();
    if (t == 0) {
        int a = 0;
        #pragma unroll
        for (int w = 0; w < 4; ++w) { int tmp = woff[w]; woff[w] = a; a += tmp; }
    }
    __syncthreads();
    if (i < N_NODES) g_rowptr[i] = g_cpre[blockIdx.x] + woff[wv] + (x - v);
}

__global__ void fill_kernel(const int* __restrict__ row, const int* __restrict__ col,
                            const float* __restrict__ w) {
    int e = blockIdx.x * blockDim.x + threadIdx.x;
    if (e < N_EDGES) {
        int r = row[e], c = col[e];
        int pos = g_rowptr[r] + atomicAdd(&g_fill[r], 1);
        g_colidx[pos] = c;
        g_normv[pos]  = g_dinv[r] * w[e] * g_dinv[c];
    }
}

// ---------------- conversions ----------------
// W [K][N] fp32 -> WT [Npad][K] fp16 (zero-pad rows >= N)
__global__ void wtrans(const float* __restrict__ W, _Float16* __restrict__ WT,
                       int K, int N, int Npad) {
    int idx = blockIdx.x * blockDim.x + threadIdx.x;
    if (idx >= Npad * K) return;
    int n = idx / K, k = idx - n * K;
    WT[idx] = (_Float16)((n < N) ? W[(size_t)k * N + n] : 0.f);
}

// labels -> interleaved fp16 [i][80] = y1[0..39] | y2[0..39]
__global__ void cvt_lab80(const float* __restrict__ lab1, const float* __restrict__ lab2,
                          _Float16* __restrict__ out) {
    int idx = blockIdx.x * blockDim.x + threadIdx.x;
    if (idx >= N_NODES * 80) return;
    int i = idx / 80, cc = idx - 80 * i;
    float v = (cc < OUT_C) ? lab1[(size_t)i * OUT_C + cc]
                           : lab2[(size_t)i * OUT_C + cc - OUT_C];
    out[idx] = (_Float16)v;
}

// BN scale/shift + ReLU + fp16 cast: g_B fp32 -> g_h16
__global__ __launch_bounds__(256) void bn_apply_cvt(const float* __restrict__ h,
                                                    _Float16* __restrict__ out,
                                                    const float* __restrict__ scale,
                                                    const float* __restrict__ shift) {
    int i = blockIdx.x * blockDim.x + threadIdx.x;   // float4-group index
    if (i >= N_NODES * (HID_C / 4)) return;
    int c = (i & 63) * 4;
    float4 v = ((const float4*)h)[i];
    half4v o;
    o.x = (_Float16)fmaxf(v.x * scale[c + 0] + shift[c + 0], 0.f);
    o.y = (_Float16)fmaxf(v.y * scale[c + 1] + shift[c + 1], 0.f);
    o.z = (_Float16)fmaxf(v.z * scale[c + 2] + shift[c + 2], 0.f);
    o.w = (_Float16)fmaxf(v.w * scale[c + 3] + shift[c + 3], 0.f);
    ((half4v*)out)[i] = o;
}

// ---------------- register-only MFMA GEMM (no LDS, no barriers) --------------
// v_mfma_f32_32x32x16_f16; A row-major (fp32 or fp16, converted in-register),
// BT [N][K] fp16. A-frag: lane holds A[m=lane&31][k=(lane>>5)*8+j].
// C/D: col=lane&31, row=(reg&3)+8*(reg>>2)+4*(lane>>5)  [m74/m101-verified].
__device__ __forceinline__ half8 load_a8(const _Float16* p) { return *(const half8*)p; }
__device__ __forceinline__ half8 load_a8(const float* p) {
    float4 a0 = *(const float4*)p;
    float4 a1 = *(const float4*)(p + 4);
    half8 h;
    h[0] = (_Float16)a0.x; h[1] = (_Float16)a0.y; h[2] = (_Float16)a0.z; h[3] = (_Float16)a0.w;
    h[4] = (_Float16)a1.x; h[5] = (_Float16)a1.y; h[6] = (_Float16)a1.z; h[7] = (_Float16)a1.w;
    return h;
}

// N=256 GEMM -> fp16 C. Block: 4 waves, wm=w>>1 rows32, wn=w&1 col-half.
template <typename AT>
__global__ __launch_bounds__(256) void gemm_h(const AT* __restrict__ A,
                                              const _Float16* __restrict__ BT,
                                              _Float16* __restrict__ C,
                                              int M, int K) {
    int w = threadIdx.x >> 6, lane = threadIdx.x & 63;
    int wm = w >> 1, wn = w & 1;
    int m0 = blockIdx.x * 64 + wm * 32;
    int nb = wn * 128;
    int l31 = lane & 31, kh = (lane >> 5) * 8;
    int arow = min(m0 + l31, M - 1);                  // clamp: no OOB reads
    const AT*       ap = A  + (size_t)arow * K + kh;
    const _Float16* bp = BT + (size_t)(nb + l31) * K + kh;
    f32x16 acc[4];
    #pragma unroll
    for (int nt = 0; nt < 4; ++nt)
        #pragma unroll
        for (int s = 0; s < 16; ++s) acc[nt][s] = 0.f;

    for (int k = 0; k < K; k += 16) {
        half8 af = load_a8(ap + k);
        #pragma unroll
        for (int nt = 0; nt < 4; ++nt) {
            half8 bf = *(const half8*)(bp + (size_t)nt * 32 * K + k);
            acc[nt] = __builtin_amdgcn_mfma_f32_32x32x16_f16(af, bf, acc[nt], 0, 0, 0);
        }
    }
    int mrow = m0 + 4 * (lane >> 5);
    #pragma unroll
    for (int nt = 0; nt < 4; ++nt) {
        int n = nb + nt * 32 + l31;
        #pragma unroll
        for (int r = 0; r < 16; ++r) {
            int m = mrow + (r & 3) + 8 * (r >> 2);
            if (m < M) C[(size_t)m * HID_C + n] = (_Float16)acc[nt][r];
        }
    }
}

// N=40 GEMM (BT padded to 64 rows) -> fp16 C [M][40]. 4 waves x 32 rows.
__global__ __launch_bounds__(256) void gemm_out(const _Float16* __restrict__ A,
                                                const _Float16* __restrict__ BT,
                                                _Float16* __restrict__ C, int M) {
    const int K = HID_C;
    int w = threadIdx.x >> 6, lane = threadIdx.x & 63;
    int m0 = blockIdx.x * 128 + w * 32;
    int l31 = lane & 31, kh = (lane >> 5) * 8;
    int arow = min(m0 + l31, M - 1);
    const _Float16* ap = A  + (size_t)arow * K + kh;
    const _Float16* bp = BT + (size_t)l31 * K + kh;
    f32x16 acc[2];
    #pragma unroll
    for (int nt = 0; nt < 2; ++nt)
        #pragma unroll
        for (int s = 0; s < 16; ++s) acc[nt][s] = 0.f;

    for (int k = 0; k < K; k += 16) {
        half8 af = *(const half8*)(ap + k);
        #pragma unroll
        for (int nt = 0; nt < 2; ++nt) {
            half8 bf = *(const half8*)(bp + (size_t)nt * 32 * K + k);
            acc[nt] = __builtin_amdgcn_mfma_f32_32x32x16_f16(af, bf, acc[nt], 0, 0, 0);
        }
    }
    int mrow = m0 + 4 * (lane >> 5);
    #pragma unroll
    for (int nt = 0; nt < 2; ++nt) {
        int n = nt * 32 + l31;
        if (n < OUT_C) {
            #pragma unroll
            for (int r = 0; r < 16; ++r) {
                int m = mrow + (r & 3) + 8 * (r >> 2);
                if (m < M) C[(size_t)m * OUT_C + n] = (_Float16)acc[nt][r];
            }
        }
    }
}

// ---------------- propagation (fp16 gathers, fp32 accumulate) ----------------
// wave per node, lane = 4 channels (half4 = 8 B); 4 nodes/block
__global__ __launch_bounds__(256) void prop256h(const _Float16* __restrict__ h,
                                                float* __restrict__ out,
                                                const float* __restrict__ bias) {
    int wv = threadIdx.x >> 6, lane = threadIdx.x & 63;
    int i = blockIdx.x * 4 + wv;               // grid = 12500 exact
    const half4v* hv = (const half4v*)h;
    float di = g_dinv[i], d2 = di * di;
    half4v r = hv[(size_t)i * 64 + lane];
    float4 acc = make_float4(d2 * (float)r.x, d2 * (float)r.y,
                             d2 * (float)r.z, d2 * (float)r.w);
    int s = g_rowptr[i], e = g_rowptr[i + 1];
    for (int k = s; k < e; ++k) {
        int   j  = g_colidx[k];
        float nv = g_normv[k];
        half4v v = hv[(size_t)j * 64 + lane];
        acc.x += nv * (float)v.x; acc.y += nv * (float)v.y;
        acc.z += nv * (float)v.z; acc.w += nv * (float)v.w;
    }
    float4 b = ((const float4*)bias)[lane];
    acc.x += b.x; acc.y += b.y; acc.z += b.z; acc.w += b.w;
    ((float4*)out)[(size_t)i * 64 + lane] = acc;
}

// GCN output: fp16 input [M][40], fp32 output (+bias) to d_out
__global__ __launch_bounds__(256) void prop40h(const _Float16* __restrict__ h,
                                               float* __restrict__ out,
                                               const float* __restrict__ bias) {
    int wv = threadIdx.x >> 6, lane = threadIdx.x & 63;
    if (lane >= OUT_C) return;
    int i = blockIdx.x * 4 + wv;
    float di = g_dinv[i];
    float acc = di * di * (float)h[(size_t)i * OUT_C + lane];
    int s = g_rowptr[i], e = g_rowptr[i + 1];
    for (int k = s; k < e; ++k)
        acc += g_normv[k] * (float)h[(size_t)g_colidx[k] * OUT_C + lane];
    out[(size_t)i * OUT_C + lane] = acc + bias[lane];
}

// paired label propagation on interleaved fp16 [i][80]; lane = half2 (2 chans)
template <bool FINAL>
__global__ __launch_bounds__(256) void prop80(const _Float16* __restrict__ y,
                                              _Float16* __restrict__ o,
                                              float* __restrict__ o1,
                                              float* __restrict__ o2) {
    int wv = threadIdx.x >> 6, lane = threadIdx.x & 63;
    if (lane >= 40) return;
    int i = blockIdx.x * 4 + wv;
    const half2v* yp = (const half2v*)y;
    float di = g_dinv[i], d2 = di * di;
    half2v sv = yp[(size_t)i * 40 + lane];
    float a0 = d2 * (float)sv.x, a1 = d2 * (float)sv.y;
    int ks = g_rowptr[i], ke = g_rowptr[i + 1];
    for (int k = ks; k < ke; ++k) {
        int   j  = g_colidx[k];
        float nv = g_normv[k];
        half2v v = yp[(size_t)j * 40 + lane];
        a0 += nv * (float)v.x; a1 += nv * (float)v.y;
    }
    if (FINAL) {
        int cc = lane * 2;
        float vals[2] = {a0, a1};
        #pragma unroll
        for (int t = 0; t < 2; ++t) {
            int c = cc + t;
            if (c < OUT_C) o1[(size_t)i * OUT_C + c] = vals[t];
            else           o2[(size_t)i * OUT_C + (c - OUT_C)] = vals[t];
        }
    } else {
        half2v ov; ov.x = (_Float16)a0; ov.y = (_Float16)a1;
        ((half2v*)o)[(size_t)i * 40 + lane] = ov;
    }
}

// ---------------- batchnorm stats (1563 blocks x 32 rows) ----------------
__global__ __launch_bounds__(256) void bn_stats2(const float* __restrict__ h, int layer) {
    int c = threadIdx.x;
    int r0 = blockIdx.x * 32;
    int rend = min(r0 + 32, N_NODES);
    float s = 0.f, ss = 0.f;
    for (int i = r0; i < rend; ++i) {
        float v = h[(size_t)i * HID_C + c];
        s += v; ss += v * v;
    }
    atomicAdd(&g_bnstat[layer * 512 + c], s);
    atomicAdd(&g_bnstat[layer * 512 + 256 + c], ss);
}

__global__ void bn_final(int layer, const float* __restrict__ gamma,
                         const float* __restrict__ beta) {
    int c = threadIdx.x;
    float sum = g_bnstat[layer * 512 + c];
    float ss  = g_bnstat[layer * 512 + 256 + c];
    float mu  = sum / (float)N_NODES;
    float var = fmaxf(ss / (float)N_NODES - mu * mu, 0.f);
    float scale = gamma[c] * rsqrtf(var + BN_EPS);
    g_bnss[layer * 512 + c]       = scale;
    g_bnss[layer * 512 + 256 + c] = beta[c] - mu * scale;
}

// ---------------- host ----------------
template <typename T>
static T* symaddr(const void* sym) {
    void* p = nullptr;
    (void)hipGetSymbolAddress(&p, sym);
    return (T*)p;
}

extern "C" void kernel_launch(void* const* d_in, const int* in_sizes, int n_in,
                              void* d_out, int out_size, void* d_ws, size_t ws_size,
                              hipStream_t stream) {
    const float* x    = (const float*)d_in[0];
    const int*   ei   = (const int*)d_in[1];
    const float* lab1 = (const float*)d_in[2];
    const float* lab2 = (const float*)d_in[3];
    const float* ew   = (const float*)d_in[4];
    const float* W0   = (const float*)d_in[5];
    const float* b0   = (const float*)d_in[6];
    const float* W1   = (const float*)d_in[7];
    const float* b1   = (const float*)d_in[8];
    const float* W2   = (const float*)d_in[9];
    const float* b2   = (const float*)d_in[10];
    const float* gg0  = (const float*)d_in[11];
    const float* be0  = (const float*)d_in[12];
    const float* gg1  = (const float*)d_in[13];
    const float* be1  = (const float*)d_in[14];

    _Float16* ph16 = symaddr<_Float16>(HIP_SYMBOL(g_h16));
    _Float16* pAh  = symaddr<_Float16>(HIP_SYMBOL(g_Ah));
    _Float16* po40 = symaddr<_Float16>(HIP_SYMBOL(g_o40h));
    _Float16* pl80a= symaddr<_Float16>(HIP_SYMBOL(g_l80a));
    _Float16* pl80b= symaddr<_Float16>(HIP_SYMBOL(g_l80b));
    _Float16* pw0t = symaddr<_Float16>(HIP_SYMBOL(g_w0t));
    _Float16* pw1t = symaddr<_Float16>(HIP_SYMBOL(g_w1t));
    _Float16* pw2t = symaddr<_Float16>(HIP_SYMBOL(g_w2t));
    float* pB   = symaddr<float>(HIP_SYMBOL(g_B));
    float* pdeg = symaddr<float>(HIP_SYMBOL(g_deg));
    int*   pcnt = symaddr<int>(HIP_SYMBOL(g_cnt));
    int*   pfil = symaddr<int>(HIP_SYMBOL(g_fill));
    float* pbst = symaddr<float>(HIP_SYMBOL(g_bnstat));
    float* pbss = symaddr<float>(HIP_SYMBOL(g_bnss));

    hipMemsetAsync(pdeg, 0, N_NODES * sizeof(float), stream);
    hipMemsetAsync(pcnt, 0, N_NODES * sizeof(int),   stream);
    hipMemsetAsync(pfil, 0, N_NODES * sizeof(int),   stream);
    hipMemsetAsync(pbst, 0, 4 * HID_C * sizeof(float), stream);

    // CSR build
    const int EB = (N_EDGES + 255) / 256;
    deg_count<<<EB, 256, 0, stream>>>(ei, ew);
    dinv_kernel<<<(N_NODES + 255) / 256, 256, 0, stream>>>();
    chunk_sum<<<N_CHUNK, 256, 0, stream>>>();
    chunk_scan<<<1, 1, 0, stream>>>();
    local_scan<<<N_CHUNK, 256, 0, stream>>>();
    fill_kernel<<<EB, 256, 0, stream>>>(ei, ei + N_EDGES, ew);

    // weight transposes + label interleave
    wtrans<<<(HID_C * IN_C + 255) / 256, 256, 0, stream>>>(W0, pw0t, IN_C, HID_C, HID_C);
    wtrans<<<(HID_C * HID_C + 255) / 256, 256, 0, stream>>>(W1, pw1t, HID_C, HID_C, HID_C);
    wtrans<<<(64 * HID_C + 255) / 256, 256, 0, stream>>>(W2, pw2t, HID_C, OUT_C, 64);
    cvt_lab80<<<(N_NODES * 80 + 255) / 256, 256, 0, stream>>>(lab1, lab2, pl80a);

    const int GB = N_PAD / 64;      // 782
    const int PB = N_NODES / 4;     // 12500
    const int SB = (N_NODES + 31) / 32;   // 1563
    const int CB = (N_NODES * 64 + 255) / 256;
    float* outf = (float*)d_out;    // fp32: out | y_hat | y_hat2

    // layer 0 (A = x fp32, converted in-register)
    gemm_h<float><<<GB, 256, 0, stream>>>(x, pw0t, pAh, N_NODES, IN_C);
    prop256h<<<PB, 256, 0, stream>>>(pAh, pB, b0);
    bn_stats2<<<SB, 256, 0, stream>>>(pB, 0);
    bn_final<<<1, 256, 0, stream>>>(0, gg0, be0);
    bn_apply_cvt<<<CB, 256, 0, stream>>>(pB, ph16, pbss, pbss + 256);

    // layer 1
    gemm_h<_Float16><<<GB, 256, 0, stream>>>(ph16, pw1t, pAh, N_NODES, HID_C);
    prop256h<<<PB, 256, 0, stream>>>(pAh, pB, b1);
    bn_stats2<<<SB, 256, 0, stream>>>(pB, 1);
    bn_final<<<1, 256, 0, stream>>>(1, gg1, be1);
    bn_apply_cvt<<<CB, 256, 0, stream>>>(pB, ph16, pbss + 512, pbss + 768);

    // layer 2
    gemm_out<<<N_PAD / 128, 256, 0, stream>>>(ph16, pw2t, po40, N_NODES);
    prop40h<<<PB, 256, 0, stream>>>(po40, outf, b2);

    // label propagation x3 (both matrices per pass, interleaved fp16)
    prop80<false><<<PB, 256, 0, stream>>>(pl80a, pl80b, nullptr, nullptr);
    prop80<false><<<PB, 256, 0, stream>>>(pl80b, pl80a, nullptr, nullptr);
    prop80<true ><<<PB, 256, 0, stream>>>(pl80a, nullptr,
                                          outf + (size_t)N_NODES * OUT_C,
                                          outf + 2 * (size_t)N_NODES * OUT_C);
}

// Round 8
// 1116.850 us; speedup vs baseline: 1.6607x; 1.0152x over previous
//
#include <hip/hip_runtime.h>

#define N_NODES 50000
#define N_EDGES 800000
#define IN_C    512
#define HID_C   256
#define OUT_C   40
#define BN_EPS  1e-5f
#define N_CHUNK ((N_NODES + 255) / 256)   // 196

typedef _Float16 half2v __attribute__((ext_vector_type(2)));
typedef _Float16 half4v __attribute__((ext_vector_type(4)));
typedef _Float16 half8  __attribute__((ext_vector_type(8)));
typedef float    f32x16 __attribute__((ext_vector_type(16)));

// ---------------- static device buffers ----------------
__device__ _Float16 g_h16 [(size_t)N_NODES * HID_C]; // BN+ReLU'd hidden (fp16)
__device__ _Float16 g_Ah  [(size_t)N_NODES * HID_C]; // gemm out (fp16)
__device__ _Float16 g_P   [(size_t)N_NODES * HID_C]; // prop out (fp16, pre-BN)
__device__ _Float16 g_o40h[(size_t)N_NODES * OUT_C]; // out-layer gemm (fp16)
__device__ _Float16 g_l80a[(size_t)N_NODES * 80];    // labels interleaved y1|y2 fp16
__device__ _Float16 g_l80b[(size_t)N_NODES * 80];
__device__ _Float16 g_w0t[HID_C * IN_C];             // W0^T [256][512]
__device__ _Float16 g_w1t[HID_C * HID_C];            // W1^T [256][256]
__device__ _Float16 g_w2t[64 * HID_C];               // W2^T padded [64][256]
__device__ float g_deg [N_NODES];
__device__ float g_dinv[N_NODES];
__device__ int   g_cnt [N_NODES];
__device__ int   g_fill[N_NODES];
__device__ int   g_rowptr[N_NODES + 1];
__device__ int   g_colidx[N_EDGES];
__device__ float g_normv [N_EDGES];
__device__ float g_bnstat[4 * HID_C];                // sum0|ss0|sum1|ss1
__device__ float g_bnss  [4 * HID_C];                // scale0|shift0|scale1|shift1
__device__ int   g_csum[256];
__device__ int   g_cpre[256];

// ---------------- graph build ----------------
__global__ void deg_count(const int* __restrict__ row, const float* __restrict__ w) {
    int e = blockIdx.x * blockDim.x + threadIdx.x;
    if (e < N_EDGES) {
        int r = row[e];
        atomicAdd(&g_deg[r], w[e]);
        atomicAdd(&g_cnt[r], 1);
    }
}

__global__ void dinv_kernel() {
    int i = blockIdx.x * blockDim.x + threadIdx.x;
    if (i < N_NODES) {
        float d = g_deg[i] + 1.0f;   // + self-loop weight 1
        g_dinv[i] = (d > 0.f) ? rsqrtf(fmaxf(d, 1e-12f)) : 0.f;
    }
}

__global__ __launch_bounds__(256) void chunk_sum() {
    __shared__ int sh[256];
    int i = blockIdx.x * 256 + threadIdx.x;
    sh[threadIdx.x] = (i < N_NODES) ? g_cnt[i] : 0;
    __syncthreads();
    for (int s = 128; s > 0; s >>= 1) {
        if (threadIdx.x < s) sh[threadIdx.x] += sh[threadIdx.x + s];
        __syncthreads();
    }
    if (threadIdx.x == 0) g_csum[blockIdx.x] = sh[0];
}
__global__ void chunk_scan() {
    int acc = 0;
    for (int b = 0; b < N_CHUNK; ++b) { g_cpre[b] = acc; acc += g_csum[b]; }
    g_rowptr[N_NODES] = acc;
}
__global__ __launch_bounds__(256) void local_scan() {
    __shared__ int woff[4];
    int t = threadIdx.x, lane = t & 63, wv = t >> 6;
    int i = blockIdx.x * 256 + t;
    int v = (i < N_NODES) ? g_cnt[i] : 0;
    int x = v;
    #pragma unroll
    for (int off = 1; off < 64; off <<= 1) {
        int y = __shfl_up(x, off);
        if (lane >= off) x += y;
    }
    if (lane == 63) woff[wv] = x;
    __syncthreads();
    if (t == 0) {
        int a = 0;
        #pragma unroll
        for (int w = 0; w < 4; ++w) { int tmp = woff[w]; woff[w] = a; a += tmp; }
    }
    __syncthreads();
    if (i < N_NODES) g_rowptr[i] = g_cpre[blockIdx.x] + woff[wv] + (x - v);
}

__global__ void fill_kernel(const int* __restrict__ row, const int* __restrict__ col,
                            const float* __restrict__ w) {
    int e = blockIdx.x * blockDim.x + threadIdx.x;
    if (e < N_EDGES) {
        int r = row[e], c = col[e];
        int pos = g_rowptr[r] + atomicAdd(&g_fill[r], 1);
        g_colidx[pos] = c;
        g_normv[pos]  = g_dinv[r] * w[e] * g_dinv[c];
    }
}

// ---------------- conversions ----------------
// W [K][N] fp32 -> WT [Npad][K] fp16 (zero-pad rows >= N)
__global__ void wtrans(const float* __restrict__ W, _Float16* __restrict__ WT,
                       int K, int N, int Npad) {
    int idx = blockIdx.x * blockDim.x + threadIdx.x;
    if (idx >= Npad * K) return;
    int n = idx / K, k = idx - n * K;
    WT[idx] = (_Float16)((n < N) ? W[(size_t)k * N + n] : 0.f);
}

// labels -> interleaved fp16 [i][80] = y1[0..39] | y2[0..39]
__global__ void cvt_lab80(const float* __restrict__ lab1, const float* __restrict__ lab2,
                          _Float16* __restrict__ out) {
    int idx = blockIdx.x * blockDim.x + threadIdx.x;
    if (idx >= N_NODES * 80) return;
    int i = idx / 80, cc = idx - 80 * i;
    float v = (cc < OUT_C) ? lab1[(size_t)i * OUT_C + cc]
                           : lab2[(size_t)i * OUT_C + cc - OUT_C];
    out[idx] = (_Float16)v;
}

// BN scale/shift + ReLU on fp16: g_P -> g_h16
__global__ __launch_bounds__(256) void bn_apply16(const _Float16* __restrict__ h,
                                                  _Float16* __restrict__ out,
                                                  const float* __restrict__ scale,
                                                  const float* __restrict__ shift) {
    int i = blockIdx.x * blockDim.x + threadIdx.x;   // half4-group index
    if (i >= N_NODES * (HID_C / 4)) return;
    int c = (i & 63) * 4;
    half4v v = ((const half4v*)h)[i];
    half4v o;
    o.x = (_Float16)fmaxf((float)v.x * scale[c + 0] + shift[c + 0], 0.f);
    o.y = (_Float16)fmaxf((float)v.y * scale[c + 1] + shift[c + 1], 0.f);
    o.z = (_Float16)fmaxf((float)v.z * scale[c + 2] + shift[c + 2], 0.f);
    o.w = (_Float16)fmaxf((float)v.w * scale[c + 3] + shift[c + 3], 0.f);
    ((half4v*)out)[i] = o;
}

// ---------------- register-only MFMA GEMM (no LDS, no barriers) --------------
// v_mfma_f32_32x32x16_f16; A row-major (fp32/fp16, converted in-register),
// BT [N][K] fp16. A-frag: lane holds A[m=lane&31][k=(lane>>5)*8+j].
// C/D: col=lane&31, row=(reg&3)+8*(reg>>2)+4*(lane>>5)  [m74/m101-verified].
__device__ __forceinline__ half8 load_a8(const _Float16* p) { return *(const half8*)p; }
__device__ __forceinline__ half8 load_a8(const float* p) {
    float4 a0 = *(const float4*)p;
    float4 a1 = *(const float4*)(p + 4);
    half8 h;
    h[0] = (_Float16)a0.x; h[1] = (_Float16)a0.y; h[2] = (_Float16)a0.z; h[3] = (_Float16)a0.w;
    h[4] = (_Float16)a1.x; h[5] = (_Float16)a1.y; h[6] = (_Float16)a1.z; h[7] = (_Float16)a1.w;
    return h;
}

// N=256 GEMM -> fp16 C. Block = 32 rows x 256 cols; wave w takes 64-col
// quarter. All 4 waves read the SAME A rows -> L1 broadcast, A fetched once.
template <int K, typename AT>
__global__ __launch_bounds__(256) void gemm_h2(const AT* __restrict__ A,
                                               const _Float16* __restrict__ BT,
                                               _Float16* __restrict__ C, int M) {
    int w = threadIdx.x >> 6, lane = threadIdx.x & 63;
    int m0 = blockIdx.x * 32;
    int nb = w * 64;
    int l31 = lane & 31, kh = (lane >> 5) * 8;
    int arow = min(m0 + l31, M - 1);                  // clamp: no OOB reads
    const AT*       ap = A  + (size_t)arow * K + kh;
    const _Float16* bp = BT + (size_t)(nb + l31) * K + kh;
    f32x16 acc[2];
    #pragma unroll
    for (int nt = 0; nt < 2; ++nt)
        #pragma unroll
        for (int s = 0; s < 16; ++s) acc[nt][s] = 0.f;

    #pragma unroll 2
    for (int k = 0; k < K; k += 16) {
        half8 af = load_a8(ap + k);
        half8 b0 = *(const half8*)(bp + k);
        half8 b1 = *(const half8*)(bp + (size_t)32 * K + k);
        acc[0] = __builtin_amdgcn_mfma_f32_32x32x16_f16(af, b0, acc[0], 0, 0, 0);
        acc[1] = __builtin_amdgcn_mfma_f32_32x32x16_f16(af, b1, acc[1], 0, 0, 0);
    }
    int mrow = m0 + 4 * (lane >> 5);
    #pragma unroll
    for (int nt = 0; nt < 2; ++nt) {
        int n = nb + nt * 32 + l31;
        #pragma unroll
        for (int r = 0; r < 16; ++r) {
            int m = mrow + (r & 3) + 8 * (r >> 2);
            if (m < M) C[(size_t)m * HID_C + n] = (_Float16)acc[nt][r];
        }
    }
}

// N=40 GEMM (BT padded to 64 rows) -> fp16 C [M][40]. 4 waves x 32 rows.
__global__ __launch_bounds__(256) void gemm_out(const _Float16* __restrict__ A,
                                                const _Float16* __restrict__ BT,
                                                _Float16* __restrict__ C, int M) {
    const int K = HID_C;
    int w = threadIdx.x >> 6, lane = threadIdx.x & 63;
    int m0 = blockIdx.x * 128 + w * 32;
    int l31 = lane & 31, kh = (lane >> 5) * 8;
    int arow = min(m0 + l31, M - 1);
    const _Float16* ap = A  + (size_t)arow * K + kh;
    const _Float16* bp = BT + (size_t)l31 * K + kh;
    f32x16 acc[2];
    #pragma unroll
    for (int nt = 0; nt < 2; ++nt)
        #pragma unroll
        for (int s = 0; s < 16; ++s) acc[nt][s] = 0.f;

    #pragma unroll 2
    for (int k = 0; k < K; k += 16) {
        half8 af = *(const half8*)(ap + k);
        #pragma unroll
        for (int nt = 0; nt < 2; ++nt) {
            half8 bf = *(const half8*)(bp + (size_t)nt * 32 * K + k);
            acc[nt] = __builtin_amdgcn_mfma_f32_32x32x16_f16(af, bf, acc[nt], 0, 0, 0);
        }
    }
    int mrow = m0 + 4 * (lane >> 5);
    #pragma unroll
    for (int nt = 0; nt < 2; ++nt) {
        int n = nt * 32 + l31;
        if (n < OUT_C) {
            #pragma unroll
            for (int r = 0; r < 16; ++r) {
                int m = mrow + (r & 3) + 8 * (r >> 2);
                if (m < M) C[(size_t)m * OUT_C + n] = (_Float16)acc[nt][r];
            }
        }
    }
}

// ---------------- propagation (fp16 gathers, fp32 accumulate, fp16 out) ------
// wave per node, lane = 4 channels (half4 = 8 B); 4 nodes/block
__global__ __launch_bounds__(256) void prop256h(const _Float16* __restrict__ h,
                                                _Float16* __restrict__ out,
                                                const float* __restrict__ bias) {
    int wv = threadIdx.x >> 6, lane = threadIdx.x & 63;
    int i = blockIdx.x * 4 + wv;               // grid = 12500 exact
    const half4v* hv = (const half4v*)h;
    float di = g_dinv[i], d2 = di * di;
    half4v r = hv[(size_t)i * 64 + lane];
    float4 acc = make_float4(d2 * (float)r.x, d2 * (float)r.y,
                             d2 * (float)r.z, d2 * (float)r.w);
    int s = g_rowptr[i], e = g_rowptr[i + 1];
    for (int k = s; k < e; ++k) {
        int   j  = g_colidx[k];
        float nv = g_normv[k];
        half4v v = hv[(size_t)j * 64 + lane];
        acc.x += nv * (float)v.x; acc.y += nv * (float)v.y;
        acc.z += nv * (float)v.z; acc.w += nv * (float)v.w;
    }
    float4 b = ((const float4*)bias)[lane];
    half4v o;
    o.x = (_Float16)(acc.x + b.x); o.y = (_Float16)(acc.y + b.y);
    o.z = (_Float16)(acc.z + b.z); o.w = (_Float16)(acc.w + b.w);
    ((half4v*)out)[(size_t)i * 64 + lane] = o;
}

// GCN output: fp16 input [M][40], fp32 output (+bias) to d_out
__global__ __launch_bounds__(256) void prop40h(const _Float16* __restrict__ h,
                                               float* __restrict__ out,
                                               const float* __restrict__ bias) {
    int wv = threadIdx.x >> 6, lane = threadIdx.x & 63;
    if (lane >= OUT_C) return;
    int i = blockIdx.x * 4 + wv;
    float di = g_dinv[i];
    float acc = di * di * (float)h[(size_t)i * OUT_C + lane];
    int s = g_rowptr[i], e = g_rowptr[i + 1];
    for (int k = s; k < e; ++k)
        acc += g_normv[k] * (float)h[(size_t)g_colidx[k] * OUT_C + lane];
    out[(size_t)i * OUT_C + lane] = acc + bias[lane];
}

// paired label propagation on interleaved fp16 [i][80]; lane = half2 (2 chans)
template <bool FINAL>
__global__ __launch_bounds__(256) void prop80(const _Float16* __restrict__ y,
                                              _Float16* __restrict__ o,
                                              float* __restrict__ o1,
                                              float* __restrict__ o2) {
    int wv = threadIdx.x >> 6, lane = threadIdx.x & 63;
    if (lane >= 40) return;
    int i = blockIdx.x * 4 + wv;
    const half2v* yp = (const half2v*)y;
    float di = g_dinv[i], d2 = di * di;
    half2v sv = yp[(size_t)i * 40 + lane];
    float a0 = d2 * (float)sv.x, a1 = d2 * (float)sv.y;
    int ks = g_rowptr[i], ke = g_rowptr[i + 1];
    for (int k = ks; k < ke; ++k) {
        int   j  = g_colidx[k];
        float nv = g_normv[k];
        half2v v = yp[(size_t)j * 40 + lane];
        a0 += nv * (float)v.x; a1 += nv * (float)v.y;
    }
    if (FINAL) {
        int cc = lane * 2;
        float vals[2] = {a0, a1};
        #pragma unroll
        for (int t = 0; t < 2; ++t) {
            int c = cc + t;
            if (c < OUT_C) o1[(size_t)i * OUT_C + c] = vals[t];
            else           o2[(size_t)i * OUT_C + (c - OUT_C)] = vals[t];
        }
    } else {
        half2v ov; ov.x = (_Float16)a0; ov.y = (_Float16)a1;
        ((half2v*)o)[(size_t)i * 40 + lane] = ov;
    }
}

// ---------------- batchnorm stats (fp16 input, 32 rows/block) ----------------
__global__ __launch_bounds__(256) void bn_stats16(const _Float16* __restrict__ h, int layer) {
    int c = threadIdx.x;
    int r0 = blockIdx.x * 32;
    int rend = min(r0 + 32, N_NODES);
    float s = 0.f, ss = 0.f;
    for (int i = r0; i < rend; ++i) {
        float v = (float)h[(size_t)i * HID_C + c];
        s += v; ss += v * v;
    }
    atomicAdd(&g_bnstat[layer * 512 + c], s);
    atomicAdd(&g_bnstat[layer * 512 + 256 + c], ss);
}

__global__ void bn_final(int layer, const float* __restrict__ gamma,
                         const float* __restrict__ beta) {
    int c = threadIdx.x;
    float sum = g_bnstat[layer * 512 + c];
    float ss  = g_bnstat[layer * 512 + 256 + c];
    float mu  = sum / (float)N_NODES;
    float var = fmaxf(ss / (float)N_NODES - mu * mu, 0.f);
    float scale = gamma[c] * rsqrtf(var + BN_EPS);
    g_bnss[layer * 512 + c]       = scale;
    g_bnss[layer * 512 + 256 + c] = beta[c] - mu * scale;
}

// ---------------- host ----------------
template <typename T>
static T* symaddr(const void* sym) {
    void* p = nullptr;
    (void)hipGetSymbolAddress(&p, sym);
    return (T*)p;
}

extern "C" void kernel_launch(void* const* d_in, const int* in_sizes, int n_in,
                              void* d_out, int out_size, void* d_ws, size_t ws_size,
                              hipStream_t stream) {
    const float* x    = (const float*)d_in[0];
    const int*   ei   = (const int*)d_in[1];
    const float* lab1 = (const float*)d_in[2];
    const float* lab2 = (const float*)d_in[3];
    const float* ew   = (const float*)d_in[4];
    const float* W0   = (const float*)d_in[5];
    const float* b0   = (const float*)d_in[6];
    const float* W1   = (const float*)d_in[7];
    const float* b1   = (const float*)d_in[8];
    const float* W2   = (const float*)d_in[9];
    const float* b2   = (const float*)d_in[10];
    const float* gg0  = (const float*)d_in[11];
    const float* be0  = (const float*)d_in[12];
    const float* gg1  = (const float*)d_in[13];
    const float* be1  = (const float*)d_in[14];

    _Float16* ph16 = symaddr<_Float16>(HIP_SYMBOL(g_h16));
    _Float16* pAh  = symaddr<_Float16>(HIP_SYMBOL(g_Ah));
    _Float16* pP   = symaddr<_Float16>(HIP_SYMBOL(g_P));
    _Float16* po40 = symaddr<_Float16>(HIP_SYMBOL(g_o40h));
    _Float16* pl80a= symaddr<_Float16>(HIP_SYMBOL(g_l80a));
    _Float16* pl80b= symaddr<_Float16>(HIP_SYMBOL(g_l80b));
    _Float16* pw0t = symaddr<_Float16>(HIP_SYMBOL(g_w0t));
    _Float16* pw1t = symaddr<_Float16>(HIP_SYMBOL(g_w1t));
    _Float16* pw2t = symaddr<_Float16>(HIP_SYMBOL(g_w2t));
    float* pdeg = symaddr<float>(HIP_SYMBOL(g_deg));
    int*   pcnt = symaddr<int>(HIP_SYMBOL(g_cnt));
    int*   pfil = symaddr<int>(HIP_SYMBOL(g_fill));
    float* pbst = symaddr<float>(HIP_SYMBOL(g_bnstat));
    float* pbss = symaddr<float>(HIP_SYMBOL(g_bnss));

    hipMemsetAsync(pdeg, 0, N_NODES * sizeof(float), stream);
    hipMemsetAsync(pcnt, 0, N_NODES * sizeof(int),   stream);
    hipMemsetAsync(pfil, 0, N_NODES * sizeof(int),   stream);
    hipMemsetAsync(pbst, 0, 4 * HID_C * sizeof(float), stream);

    // CSR build
    const int EB = (N_EDGES + 255) / 256;
    deg_count<<<EB, 256, 0, stream>>>(ei, ew);
    dinv_kernel<<<(N_NODES + 255) / 256, 256, 0, stream>>>();
    chunk_sum<<<N_CHUNK, 256, 0, stream>>>();
    chunk_scan<<<1, 1, 0, stream>>>();
    local_scan<<<N_CHUNK, 256, 0, stream>>>();
    fill_kernel<<<EB, 256, 0, stream>>>(ei, ei + N_EDGES, ew);

    // weight transposes + label interleave
    wtrans<<<(HID_C * IN_C + 255) / 256, 256, 0, stream>>>(W0, pw0t, IN_C, HID_C, HID_C);
    wtrans<<<(HID_C * HID_C + 255) / 256, 256, 0, stream>>>(W1, pw1t, HID_C, HID_C, HID_C);
    wtrans<<<(64 * HID_C + 255) / 256, 256, 0, stream>>>(W2, pw2t, HID_C, OUT_C, 64);
    cvt_lab80<<<(N_NODES * 80 + 255) / 256, 256, 0, stream>>>(lab1, lab2, pl80a);

    const int GB32 = (N_NODES + 31) / 32;    // 1563
    const int PB   = N_NODES / 4;            // 12500
    const int CB   = (N_NODES * 64 + 255) / 256;
    float* outf = (float*)d_out;    // fp32: out | y_hat | y_hat2

    // layer 0 (A = x fp32, converted in-register)
    gemm_h2<IN_C, float><<<GB32, 256, 0, stream>>>(x, pw0t, pAh, N_NODES);
    prop256h<<<PB, 256, 0, stream>>>(pAh, pP, b0);
    bn_stats16<<<GB32, 256, 0, stream>>>(pP, 0);
    bn_final<<<1, 256, 0, stream>>>(0, gg0, be0);
    bn_apply16<<<CB, 256, 0, stream>>>(pP, ph16, pbss, pbss + 256);

    // layer 1
    gemm_h2<HID_C, _Float16><<<GB32, 256, 0, stream>>>(ph16, pw1t, pAh, N_NODES);
    prop256h<<<PB, 256, 0, stream>>>(pAh, pP, b1);
    bn_stats16<<<GB32, 256, 0, stream>>>(pP, 1);
    bn_final<<<1, 256, 0, stream>>>(1, gg1, be1);
    bn_apply16<<<CB, 256, 0, stream>>>(pP, ph16, pbss + 512, pbss + 768);

    // layer 2
    gemm_out<<<(N_NODES + 127) / 128, 256, 0, stream>>>(ph16, pw2t, po40, N_NODES);
    prop40h<<<PB, 256, 0, stream>>>(po40, outf, b2);

    // label propagation x3 (both matrices per pass, interleaved fp16)
    prop80<false><<<PB, 256, 0, stream>>>(pl80a, pl80b, nullptr, nullptr);
    prop80<false><<<PB, 256, 0, stream>>>(pl80b, pl80a, nullptr, nullptr);
    prop80<true ><<<PB, 256, 0, stream>>>(pl80a, nullptr,
                                          outf + (size_t)N_NODES * OUT_C,
                                          outf + 2 * (size_t)N_NODES * OUT_C);
}